// Round 13
// baseline (349.339 us; speedup 1.0000x reference)
//
#include <hip/hip_runtime.h>

#define D 256
#define DA 288                     // augmented K (one extra 32-block)
#define NKB 9                      // DA/32
#define NKB_P 8                    // pairwise uses un-augmented 256
#define NE 8192
#define NZ 16384
#define BM 128
#define AM 256                     // argmin rows per block (4 waves x 64 rows)
#define BK 32
#define LDA (BM + 4)               // fp32 k-major LDS stride (fix_split role)
#define NB (NE / BM)
#define NTRI (NB * (NB + 1) / 2)
#define NSPLIT_A 16
#define SPLIT_NA (NE / NSPLIT_A)   // 512
#define GAPTH_A 0.4096f            // 1e-4 score units * 2^12 (acc units)
#define GAPTH_EFF 0.48f            // + 0.0625 trunc-quantization margin (10-bit key trunc)
#define LDM 17
#define NGB (NZ / 4)               // gather blocks = 4096
#define NCH_A (SPLIT_NA / 32)      // 16 chunks of 32 cols (argmin)
#define AUNITS (2 * NKB)           // 18 staging units per argmin chunk
#define PUNITS (2 * NKB_P)         // 16 staging units per pairwise chunk
#define NBLK_ARG (NZ / AM * NSPLIT_A)   // 1024 argmin-role blocks
#define NBLK_BIG (NBLK_ARG + NTRI)      // + 2080 pairwise-role blocks
#define NBLK_CVT (NZ / 64 + NE / 64 + 96)   // 256 z-cvt + 128 e-cvt + 96 pre
#define NBLK_FIX (1024 + 128)               // fix_split + fix_cand roles

// fp32-path LDS swizzle (verified R4-R11, fix_split role only)
#define SROT(kk) (8 * ((((kk) >> 2)) & 3))
#define SWZR(kk, r) ((((r) + SROT(kk)) & 127))

typedef _Float16 f16x8 __attribute__((ext_vector_type(8)));
typedef _Float16 f16x4 __attribute__((ext_vector_type(4)));
typedef float f32x4 __attribute__((ext_vector_type(4)));

#define MFMA16(a, b, c) __builtin_amdgcn_mfma_f32_16x16x32_f16(a, b, c, 0, 0, 0)

// async global->LDS, 16B/lane; LDS dest = uniform base + lane*16
__device__ __forceinline__ void g2l16(const void* g, void* lds) {
    __builtin_amdgcn_global_load_lds(
        (const __attribute__((address_space(1))) void*)g,
        (__attribute__((address_space(3))) void*)lds, 16, 0, 0);
}

__device__ __forceinline__ unsigned umax(unsigned a, unsigned b) { return a > b ? a : b; }
__device__ __forceinline__ unsigned umin(unsigned a, unsigned b) { return a < b ? a : b; }

// ---------------- workspace layout (bytes) ----------------
#define WS_SUMS   0                            // double[4]: gsum (diff2)
#define WS_CNT    64                           // int[32]: 16 lists + cand@16 + ticket@20
#define WS_ZSQ    256                          // float[NZ]
#define WS_ESQ    (WS_ZSQ + NZ * 4)            // float[NE]
#define WS_IDX    (WS_ESQ + NE * 4)            // int[NZ]
#define WS_KP1    (WS_IDX + NZ * 4)            // u32 keys1 [NZ*16]
#define WS_KP2    (WS_KP1 + NZ * NSPLIT_A * 4) // u32 keys2 [NZ*16]
#define WS_RMX    (WS_KP2 + NZ * NSPLIT_A * 4) // uint[NE]
#define WS_RMN    (WS_RMX + NE * 4)            // (unused, layout kept)
#define WS_PACK   (WS_RMN + NE * 4)            // u64[NZ]
#define WS_GPART  (WS_PACK + NZ * 8)           // (unused, layout kept)
#define WS_LISTS  (WS_GPART + NGB * 8)         // int[16][NZ]  (heavy fallback lists)
#define WS_ZHF    (WS_LISTS + NZ * NSPLIT_A * 4)   // frag-major f16 z
#define WS_EHF    (WS_ZHF + (size_t)(NZ / 16) * NKB * 64 * 8 * 2)
// candidate (row,col) pairs: reuse zhf region (dead after k_big)
#define WS_CAND   WS_ZHF

__device__ __forceinline__ float waveReduceSumF(float v) {
    v += __shfl_down(v, 32); v += __shfl_down(v, 16); v += __shfl_down(v, 8);
    v += __shfl_down(v, 4);  v += __shfl_down(v, 2);  v += __shfl_down(v, 1);
    return v;
}
__device__ __forceinline__ double waveReduceSumD(double v) {
    v += __shfl_down(v, 32); v += __shfl_down(v, 16); v += __shfl_down(v, 8);
    v += __shfl_down(v, 4);  v += __shfl_down(v, 2);  v += __shfl_down(v, 1);
    return v;
}

// np.sum(x*x) bit-exact for one 256-elem row (numpy pairwise summation)
__device__ __forceinline__ float rowsq256(const float* __restrict__ p) {
    float h[2];
#pragma unroll
    for (int half = 0; half < 2; ++half) {
        const float* q = p + half * 128;
        float4 a0 = *(const float4*)&q[0];
        float4 a1 = *(const float4*)&q[4];
        float r0 = __fmul_rn(a0.x, a0.x);
        float r1 = __fmul_rn(a0.y, a0.y);
        float r2 = __fmul_rn(a0.z, a0.z);
        float r3 = __fmul_rn(a0.w, a0.w);
        float r4 = __fmul_rn(a1.x, a1.x);
        float r5 = __fmul_rn(a1.y, a1.y);
        float r6 = __fmul_rn(a1.z, a1.z);
        float r7 = __fmul_rn(a1.w, a1.w);
#pragma unroll
        for (int i = 8; i < 128; i += 8) {
            const float4 b0 = *(const float4*)&q[i];
            const float4 b1 = *(const float4*)&q[i + 4];
            r0 = __fadd_rn(r0, __fmul_rn(b0.x, b0.x));
            r1 = __fadd_rn(r1, __fmul_rn(b0.y, b0.y));
            r2 = __fadd_rn(r2, __fmul_rn(b0.z, b0.z));
            r3 = __fadd_rn(r3, __fmul_rn(b0.w, b0.w));
            r4 = __fadd_rn(r4, __fmul_rn(b1.x, b1.x));
            r5 = __fadd_rn(r5, __fmul_rn(b1.y, b1.y));
            r6 = __fadd_rn(r6, __fmul_rn(b1.z, b1.z));
            r7 = __fadd_rn(r7, __fmul_rn(b1.w, b1.w));
        }
        const float t01 = __fadd_rn(r0, r1);
        const float t23 = __fadd_rn(r2, r3);
        const float t45 = __fadd_rn(r4, r5);
        const float t67 = __fadd_rn(r6, r7);
        h[half] = __fadd_rn(__fadd_rn(t01, t23), __fadd_rn(t45, t67));
    }
    return __fadd_rn(h[0], h[1]);
}

// ---- fused converter + pre kernel (contiguous role split) ----
// blocks [0,256): z transpose | [256,384): emb transpose (self-computed aug
// esq from the f32 values it loads; delta vs bit-exact ~1e-12, absorbed by
// f16 rounding + GAPTH margin) | [384,480): bit-exact rowsq + inits.
__global__ __launch_bounds__(256) void k_cvt(const float* __restrict__ z,
                                             const float* __restrict__ e,
                                             f16x8* __restrict__ zf,
                                             f16x8* __restrict__ ef,
                                             float* __restrict__ zsq,
                                             float* __restrict__ esq,
                                             int* __restrict__ cnt,
                                             unsigned* __restrict__ rmx,
                                             unsigned long long* __restrict__ pack,
                                             double* __restrict__ gsum) {
    __shared__ _Float16 Ls[64 * 296];
    __shared__ float Esq[64];
    const int t = threadIdx.x;
    const int bx = blockIdx.x;
    if (bx < NZ / 64) {
        const int row0 = bx * 64;
#pragma unroll
        for (int i = 0; i < 16; ++i) {
            const int f4 = i * 256 + t;
            const int r = f4 >> 6, c4 = f4 & 63;
            const float4 v = *(const float4*)&z[(size_t)(row0 + r) * D + c4 * 4];
            f16x4 h;
            h[0] = (_Float16)v.x; h[1] = (_Float16)v.y;
            h[2] = (_Float16)v.z; h[3] = (_Float16)v.w;
            *(f16x4*)&Ls[r * 296 + c4 * 4] = h;
        }
#pragma unroll
        for (int i = 0; i < 8; ++i) {
            const int idx = i * 256 + t;
            const int r = idx >> 5, c = idx & 31;
            Ls[r * 296 + 256 + c] = (c <= 1) ? (_Float16)1.0f : (_Float16)0.0f;
        }
        __syncthreads();
        const int l = t & 63, w = t >> 6;
#pragma unroll
        for (int kb = 0; kb < NKB; ++kb) {
            const f16x8 fr = *(const f16x8*)&Ls[(w * 16 + (l & 15)) * 296 + kb * 32 + (l >> 4) * 8];
            zf[((size_t)(bx * 4 + w) * NKB + kb) * 64 + l] = fr;
        }
    } else if (bx < NZ / 64 + NE / 64) {
        const int eb = bx - NZ / 64;
        const int row0 = eb * 64;
        // load + per-row sum-of-squares (wave w holds rows {i*4+w}, one
        // float4/lane); esq' error vs bit-exact ~1e-12 -> negligible in f16 aug
#pragma unroll
        for (int i = 0; i < 16; ++i) {
            const int f4 = i * 256 + t;
            const int r = f4 >> 6, c4 = f4 & 63;
            const float4 v = *(const float4*)&e[(size_t)(row0 + r) * D + c4 * 4];
            f16x4 h;
            h[0] = (_Float16)(v.x * 8192.0f); h[1] = (_Float16)(v.y * 8192.0f);
            h[2] = (_Float16)(v.z * 8192.0f); h[3] = (_Float16)(v.w * 8192.0f);
            *(f16x4*)&Ls[r * 296 + c4 * 4] = h;
            float d = v.x * v.x + v.y * v.y + v.z * v.z + v.w * v.w;
            d = waveReduceSumF(d);
            if ((t & 63) == 0) Esq[r] = d;
        }
        __syncthreads();
#pragma unroll
        for (int i = 0; i < 8; ++i) {
            const int idx = i * 256 + t;
            const int r = idx >> 5, c = idx & 31;
            _Float16 av = (_Float16)0.0f;
            if (c == 0) av = (_Float16)(Esq[r] * -4096.0f);
            if (c == 1) av = (_Float16)512.0f;
            Ls[r * 296 + 256 + c] = av;
        }
        __syncthreads();
        const int l = t & 63, w = t >> 6;
#pragma unroll
        for (int kb = 0; kb < NKB; ++kb) {
            const f16x8 fr = *(const f16x8*)&Ls[(w * 16 + (l & 15)) * 296 + kb * 32 + (l >> 4) * 8];
            ef[((size_t)(eb * 4 + w) * NKB + kb) * 64 + l] = fr;
        }
    } else {
        const int pb = bx - (NZ / 64 + NE / 64);   // 0..95
        if (pb == 0) {
            if (t < 24) cnt[t] = 0;
            if (t == 30) gsum[0] = 0.0;
        }
        if (pb < 64) {
            const int row = pb * 256 + t;
            zsq[row] = rowsq256(z + (size_t)row * D);
            pack[row] = ~0ull;
        } else {
            const int row = (pb - 64) * 256 + t;
            esq[row] = rowsq256(e + (size_t)row * D);
            rmx[row] = 0u;
        }
    }
}

// ---- fused MFMA kernel (R9-verified contiguous role split):
// blocks 0..1023 argmin, 1024..3103 pairwise (max-only; min_d==0 provably).
__global__ __launch_bounds__(256, 2) void k_big(
        const f16x8* __restrict__ zf, const f16x8* __restrict__ ef,
        const float* __restrict__ esq,
        unsigned* __restrict__ kp1, unsigned* __restrict__ kp2,
        unsigned* __restrict__ rmxg) {
    __shared__ __align__(16) char Sh[2 * AUNITS * 1024];   // 36864 B

    const int t = threadIdx.x;
    const int l = t & 63;
    const int w = t >> 6;
    const int quad = l >> 4;
    const int l15 = l & 15;

    if (blockIdx.x < NBLK_ARG) {
        // ================= argmin role (R7-verified body) =================
        _Float16 (*Bsm)[AUNITS * 512] = (_Float16(*)[AUNITS * 512])Sh;
        const int lin = blockIdx.x;
        const int rowblk = lin & 63;          // preserves (x=64, y=16) linearization
        const int sp = lin >> 6;
        const int row0 = rowblk * AM;
        const int arb0 = rowblk * 16 + w * 4;

        f16x8 ah[4][NKB];
#pragma unroll
        for (int mi = 0; mi < 4; ++mi)
#pragma unroll
            for (int kb = 0; kb < NKB; ++kb)
                ah[mi][kb] = zf[((size_t)(arb0 + mi) * NKB + kb) * 64 + l];

        unsigned b1[16], b2[16];
#pragma unroll
        for (int s = 0; s < 16; ++s) { b1[s] = 0u; b2[s] = 0u; }

        const char* gp[5];
#pragma unroll
        for (int ui = 0; ui < 5; ++ui) {
            const int u = w + ui * 4;
            const int uc = (u < AUNITS) ? u : 0;
            const int nj = uc / NKB, kb = uc - nj * NKB;
            gp[ui] = (const char*)&ef[((size_t)(sp * 32 + nj) * NKB + kb) * 64 + l];
        }

        auto stage = [&](size_t choff, int buf) {
            char* lb = (char*)&Bsm[0][0] + buf * (AUNITS * 1024);
#pragma unroll
            for (int ui = 0; ui < 5; ++ui) {
                const int u = w + ui * 4;
                if (u < AUNITS) g2l16(gp[ui] + choff, lb + u * 1024);
            }
        };

        auto ins = [&](unsigned key, int s) {
            unsigned b2n;
            asm("v_med3_u32 %0, %1, %2, %3"
                : "=v"(b2n) : "v"(key), "v"(b1[s]), "v"(b2[s]));
            b2[s] = b2n;
            b1[s] = umax(b1[s], key);
        };

        stage(0, 0);
        const f32x4 Zv = (f32x4){0.f, 0.f, 0.f, 0.f};
        int inv0 = 1023 - l15;
        for (int ch = 0; ch < NCH_A; ++ch) {
            const int buf = ch & 1;
            __syncthreads();
            if (ch + 1 < NCH_A) stage((size_t)(ch + 1) * 18432u, buf ^ 1);

            const unsigned invA = (unsigned)inv0;
            const unsigned invB = (unsigned)(inv0 - 16);

            f32x4 acc0[4], acc1[4];
            {
                const f16x8 bh = *(const f16x8*)&Bsm[buf][(0 * NKB + 0) * 512 + l * 8];
#pragma unroll
                for (int mi = 0; mi < 4; ++mi) acc0[mi] = MFMA16(ah[mi][0], bh, Zv);
            }
#pragma unroll
            for (int kb = 1; kb < NKB; ++kb) {
                const f16x8 bh = *(const f16x8*)&Bsm[buf][(0 * NKB + kb) * 512 + l * 8];
#pragma unroll
                for (int mi = 0; mi < 4; ++mi) acc0[mi] = MFMA16(ah[mi][kb], bh, acc0[mi]);
            }
            {
                const f16x8 bh = *(const f16x8*)&Bsm[buf][(1 * NKB + 0) * 512 + l * 8];
#pragma unroll
                for (int mi = 0; mi < 4; ++mi) acc1[mi] = MFMA16(ah[mi][0], bh, Zv);
            }
#pragma unroll
            for (int kb = 1; kb < NKB; ++kb) {
                const f16x8 bh = *(const f16x8*)&Bsm[buf][(1 * NKB + kb) * 512 + l * 8];
#pragma unroll
                for (int mi = 0; mi < 4; ++mi) acc1[mi] = MFMA16(ah[mi][kb], bh, acc1[mi]);
#pragma unroll
                for (int e = 2 * (kb - 1); e < 2 * (kb - 1) + 2; ++e) {
                    const int mi0 = e >> 2, r0 = e & 3;
                    ins((__float_as_uint(acc0[mi0][r0]) & 0xFFFFFC00u) | invA, e);
                }
            }
#pragma unroll
            for (int mi = 0; mi < 4; ++mi)
#pragma unroll
                for (int r = 0; r < 4; ++r)
                    ins((__float_as_uint(acc1[mi][r]) & 0xFFFFFC00u) | invB, mi * 4 + r);

            inv0 -= 32;
        }

#pragma unroll
        for (int s = 0; s < 16; ++s) {
            unsigned v1 = b1[s], v2 = b2[s];
#pragma unroll
            for (int m = 1; m <= 8; m <<= 1) {
                const unsigned o1 = __shfl_xor(v1, m);
                const unsigned o2 = __shfl_xor(v2, m);
                const unsigned n2 = umax(umin(v1, o1), umax(v2, o2));
                v1 = umax(v1, o1);
                v2 = n2;
            }
            if (l15 == 0) {
                const int mi = s >> 2, r = s & 3;
                const int row = row0 + w * 64 + mi * 16 + quad * 4 + r;
                kp1[(size_t)row * NSPLIT_A + sp] = v1;
                kp2[(size_t)row * NSPLIT_A + sp] = v2;
            }
        }
    } else {
        // ================= pairwise role (max-only) =================
        _Float16 (*Bsm)[PUNITS * 512] = (_Float16(*)[PUNITS * 512])Sh;
        int p = blockIdx.x - NBLK_ARG;
        int bi = 0;
        while (p >= NB - bi) { p -= NB - bi; ++bi; }
        const int bj = bi + p;
        const int row0 = bi * BM;
        const int c0 = bj * BM;

        float sR[8], sC[8];
#pragma unroll
        for (int mi = 0; mi < 2; ++mi)
#pragma unroll
            for (int r = 0; r < 4; ++r)
                sR[mi * 4 + r] = esq[row0 + w * 32 + mi * 16 + quad * 4 + r];
#pragma unroll
        for (int nj = 0; nj < 8; ++nj) sC[nj] = esq[c0 + nj * 16 + l15];

        const int arb = bi * 8 + w * 2;
        const int cfb = bj * 8;

        f16x8 ah[2][NKB_P];
#pragma unroll
        for (int kb = 0; kb < NKB_P; ++kb) {
            ah[0][kb] = ef[((size_t)arb * NKB + kb) * 64 + l];
            ah[1][kb] = ef[((size_t)(arb + 1) * NKB + kb) * 64 + l];
        }

        float rmx[8], cmx[8];
#pragma unroll
        for (int s = 0; s < 8; ++s) { rmx[s] = 0.f; cmx[s] = 0.f; }

        auto stage = [&](int ch, int buf) {
            for (int u = w; u < PUNITS; u += 4) {
                const int nj = u >> 3, kb = u & 7;
                g2l16(&ef[((size_t)(cfb + ch * 2 + nj) * NKB + kb) * 64 + l],
                      &Bsm[buf][u * 512]);
            }
        };

        stage(0, 0);
        for (int ch = 0; ch < 4; ++ch) {            // 4 chunks x 32 cols = 128
            const int buf = ch & 1;
            __syncthreads();
            if (ch + 1 < 4) stage(ch + 1, buf ^ 1);

            f32x4 acc[2][2];
#pragma unroll
            for (int mi = 0; mi < 2; ++mi)
#pragma unroll
                for (int nj = 0; nj < 2; ++nj) acc[mi][nj] = (f32x4){0.f, 0.f, 0.f, 0.f};

#pragma unroll
            for (int kb = 0; kb < NKB_P; ++kb) {
                const f16x8 bh0 = *(const f16x8*)&Bsm[buf][(0 * 8 + kb) * 512 + l * 8];
                const f16x8 bh1 = *(const f16x8*)&Bsm[buf][(1 * 8 + kb) * 512 + l * 8];
#pragma unroll
                for (int mi = 0; mi < 2; ++mi) {
                    acc[mi][0] = MFMA16(ah[mi][kb], bh0, acc[mi][0]);
                    acc[mi][1] = MFMA16(ah[mi][kb], bh1, acc[mi][1]);
                }
            }

#pragma unroll
            for (int nj = 0; nj < 2; ++nj) {
                const int cidx = ch * 2 + nj;
#pragma unroll
                for (int mi = 0; mi < 2; ++mi)
#pragma unroll
                    for (int r = 0; r < 4; ++r) {
                        const int s = mi * 4 + r;
                        const float t1 = __fadd_rn(sR[s], sC[cidx]);
                        const float d2 = fmaf(-0x1p-25f, acc[mi][nj][r], t1);
                        const float d2c = fmaxf(d2, 0.f);
                        rmx[s] = fmaxf(rmx[s], d2c);
                        cmx[cidx] = fmaxf(cmx[cidx], d2c);
                    }
            }
        }

        // rows: butterfly across the 16 lanes of the quad group, then atomics
#pragma unroll
        for (int s = 0; s < 8; ++s) {
#pragma unroll
            for (int m = 1; m <= 8; m <<= 1)
                rmx[s] = fmaxf(rmx[s], __shfl_xor(rmx[s], m));
        }
        if (l15 == 0) {
#pragma unroll
            for (int s = 0; s < 8; ++s) {
                const int mi = s >> 2, r = s & 3;
                const int row = row0 + w * 32 + mi * 16 + quad * 4 + r;
                atomicMax(&rmxg[row], __float_as_uint(rmx[s]));
            }
        }

        // cols: butterfly across quads, LDS across waves (reuse Bsm), then atomics
#pragma unroll
        for (int nj = 0; nj < 8; ++nj) {
#pragma unroll
            for (int m = 16; m <= 32; m <<= 1)
                cmx[nj] = fmaxf(cmx[nj], __shfl_xor(cmx[nj], m));
        }
        __syncthreads();   // all chunk reads done; Bsm reusable
        float* Mx = (float*)&Bsm[0][0];          // [4][128]
        if (quad == 0) {
#pragma unroll
            for (int nj = 0; nj < 8; ++nj)
                Mx[w * 128 + nj * 16 + l15] = cmx[nj];
        }
        __syncthreads();
        if (t < BM) {
            float mx = Mx[t];
#pragma unroll
            for (int ww = 1; ww < 4; ++ww)
                mx = fmaxf(mx, Mx[ww * 128 + t]);
            atomicMax(&rmxg[c0 + t], __float_as_uint(mx));
        }
    }
}

// merge split keys; provisional idx; emit per-split top-1 candidates for
// near-tie rows; full-split fallback only when a split's SECOND-best is also
// in range.
__global__ __launch_bounds__(256) void k_merge(const unsigned* __restrict__ kp1,
                                               const unsigned* __restrict__ kp2,
                                               int* __restrict__ idxbuf,
                                               float* __restrict__ outidx,
                                               int* __restrict__ cnt,
                                               int* __restrict__ lists,
                                               unsigned long long* __restrict__ cand) {
    const int n = blockIdx.x * 256 + threadIdx.x;
    unsigned k1v[NSPLIT_A], k2v[NSPLIT_A];
#pragma unroll
    for (int s = 0; s < NSPLIT_A; ++s) {
        k1v[s] = kp1[n * NSPLIT_A + s];
        k2v[s] = kp2[n * NSPLIT_A + s];
    }
    unsigned K1 = k1v[0]; int sb = 0;
#pragma unroll
    for (int s = 1; s < NSPLIT_A; ++s)
        if (k1v[s] > K1) { K1 = k1v[s]; sb = s; }
    unsigned K2 = 0u;
#pragma unroll
    for (int s = 0; s < NSPLIT_A; ++s) {
        const unsigned a = (s == sb) ? k2v[s] : k1v[s];
        K2 = umax(K2, a);
    }
    const int ii1 = sb * SPLIT_NA + 1023 - (int)(K1 & 1023u);
    idxbuf[n] = ii1;
    outidx[n] = (float)ii1;
    const float val1 = __uint_as_float(K1 & 0xFFFFFC00u);
    const float val2 = __uint_as_float(K2 & 0xFFFFFC00u);
    if (val1 - val2 < GAPTH_EFF) {
        const float vlim = val1 - GAPTH_EFF;    // qualify: val >= vlim
        int ncand = 0;
#pragma unroll
        for (int s = 0; s < NSPLIT_A; ++s) {
            if (__uint_as_float(k1v[s] & 0xFFFFFC00u) >= vlim) ++ncand;
            if (__uint_as_float(k2v[s] & 0xFFFFFC00u) >= vlim) {
                const int p = atomicAdd(&cnt[s], 1);
                lists[s * NZ + p] = n;
            }
        }
        const int base = atomicAdd(&cnt[16], ncand);
        int o = 0;
#pragma unroll
        for (int s = 0; s < NSPLIT_A; ++s)
            if (__uint_as_float(k1v[s] & 0xFFFFFC00u) >= vlim) {
                const int col = s * SPLIT_NA + 1023 - (int)(k1v[s] & 1023u);
                cand[base + o] = ((unsigned long long)(unsigned)n << 32) |
                                 (unsigned)col;
                ++o;
            }
    }
}

// ---- fused fp32 repair: blocks [0,1024) = fix_split role (np-bit-exact,
// exact (s,chunk,rb) mapping of the former 2D grid: x=bx&63, y=bx>>6);
// blocks [1024,1152) = fix_cand role (bit-identical fmaf chain).
__global__ __launch_bounds__(256) void k_fix(const float* __restrict__ z,
                                             const float* __restrict__ emb,
                                             const float* __restrict__ zsq,
                                             const float* __restrict__ esq,
                                             const int* __restrict__ cnt,
                                             const int* __restrict__ lists,
                                             const unsigned long long* __restrict__ cand,
                                             unsigned long long* __restrict__ pack) {
    __shared__ float As[BK * LDA];
    __shared__ float Bs[BK * LDA];
    __shared__ float Sq[BM];
    __shared__ int frow[BM];

    const int t = threadIdx.x;
    if (blockIdx.x >= 1024) {
        // ================= fix_cand role =================
        const int nc = cnt[16];
        for (int i = (blockIdx.x - 1024) * 256 + t; i < nc; i += 128 * 256) {
            const unsigned long long pr = cand[i];
            const int row = (int)(pr >> 32);
            const int col = (int)(pr & 0xffffffffu);
            const float4* zp = (const float4*)(z + (size_t)row * D);
            const float4* ep = (const float4*)(emb + (size_t)col * D);
            float acc = 0.f;
#pragma unroll
            for (int k4 = 0; k4 < D / 4; ++k4) {
                const float4 a = zp[k4];
                const float4 b = ep[k4];
                acc = fmaf(a.x, b.x, acc);
                acc = fmaf(a.y, b.y, acc);
                acc = fmaf(a.z, b.z, acc);
                acc = fmaf(a.w, b.w, acc);
            }
            const float sc = fmaf(-2.f, acc, __fadd_rn(zsq[row], esq[col]));
            const unsigned long long pk =
                ((unsigned long long)__float_as_uint(sc) << 32) | (unsigned)col;
            atomicMin(&pack[row], pk);
        }
        return;
    }

    // ================= fix_split role =================
    const int bx = blockIdx.x;
    const int xl = bx & 63;
    const int s = xl >> 2;
    const int chunk = xl & 3;
    const int ns = cnt[s];
    const int c0 = s * SPLIT_NA + chunk * BM;
    const int tr = t >> 4;
    const int tc = t & 15;
    const int sr = t >> 3;
    const int skq = t & 7;
    const int wrot = 8 * (skq & 3);

    for (int rb = bx >> 6; rb * BM < ns; rb += 16) {
        __syncthreads();
        if (t < BM) {
            const int fi = rb * BM + t;
            frow[t] = (fi < ns) ? lists[s * NZ + fi] : lists[s * NZ];
            Sq[t] = esq[c0 + t];
        }
        __syncthreads();

        float zqr[8];
#pragma unroll
        for (int i = 0; i < 8; ++i) zqr[i] = zsq[frow[tr * 8 + i]];

        float best[8];
        int bidx[8];
#pragma unroll
        for (int i = 0; i < 8; ++i) { best[i] = 3.4e38f; bidx[i] = 0; }

        float acc[8][8];
#pragma unroll
        for (int i = 0; i < 8; ++i)
#pragma unroll
            for (int j = 0; j < 8; ++j) acc[i][j] = 0.f;

        float4 pav[4], pbv[4];
#pragma unroll
        for (int q = 0; q < 4; ++q) {
            const int r = sr + 32 * q;
            pav[q] = *(const float4*)&z[(size_t)frow[r] * D + 0 + 4 * skq];
            pbv[q] = *(const float4*)&emb[(size_t)(c0 + r) * D + 0 + 4 * skq];
        }

        for (int kb = 0; kb < D; kb += BK) {
            __syncthreads();
#pragma unroll
            for (int q = 0; q < 4; ++q) {
                const int r = sr + 32 * q;
                const int rr = (r + wrot) & 127;
                As[(4 * skq + 0) * LDA + rr] = pav[q].x;
                As[(4 * skq + 1) * LDA + rr] = pav[q].y;
                As[(4 * skq + 2) * LDA + rr] = pav[q].z;
                As[(4 * skq + 3) * LDA + rr] = pav[q].w;
                Bs[(4 * skq + 0) * LDA + rr] = pbv[q].x;
                Bs[(4 * skq + 1) * LDA + rr] = pbv[q].y;
                Bs[(4 * skq + 2) * LDA + rr] = pbv[q].z;
                Bs[(4 * skq + 3) * LDA + rr] = pbv[q].w;
            }
            __syncthreads();
            if (kb + BK < D) {
#pragma unroll
                for (int q = 0; q < 4; ++q) {
                    const int r = sr + 32 * q;
                    pav[q] = *(const float4*)&z[(size_t)frow[r] * D + kb + BK + 4 * skq];
                    pbv[q] = *(const float4*)&emb[(size_t)(c0 + r) * D + kb + BK + 4 * skq];
                }
            }
#pragma unroll
            for (int k = 0; k < BK; ++k) {
                const float4 a0 = *(const float4*)&As[k * LDA + SWZR(k, tr * 8)];
                const float4 a1 = *(const float4*)&As[k * LDA + SWZR(k, tr * 8 + 4)];
                const float4 b0 = *(const float4*)&Bs[k * LDA + SWZR(k, tc * 4)];
                const float4 b1 = *(const float4*)&Bs[k * LDA + SWZR(k, 64 + tc * 4)];
                const float a[8] = {a0.x, a0.y, a0.z, a0.w, a1.x, a1.y, a1.z, a1.w};
                const float b[8] = {b0.x, b0.y, b0.z, b0.w, b1.x, b1.y, b1.z, b1.w};
#pragma unroll
                for (int i = 0; i < 8; ++i)
#pragma unroll
                    for (int j = 0; j < 8; ++j)
                        acc[i][j] = fmaf(a[i], b[j], acc[i][j]);
            }
        }
#pragma unroll
        for (int jj = 0; jj < 8; ++jj) {
            const int cloc = (jj < 4) ? (tc * 4 + jj) : (64 + tc * 4 + (jj - 4));
            const float sq = Sq[cloc];
            const int gcol = c0 + cloc;
#pragma unroll
            for (int i = 0; i < 8; ++i) {
                const float t1 = __fadd_rn(zqr[i], sq);
                const float sc = fmaf(-2.f, acc[i][jj], t1);
                if (sc < best[i]) { best[i] = sc; bidx[i] = gcol; }
            }
        }
        __syncthreads();

        float* Rs = As;
        int* Ri = (int*)Bs;
#pragma unroll
        for (int i = 0; i < 8; ++i) {
            Rs[(tr * 8 + i) * LDM + tc] = best[i];
            Ri[(tr * 8 + i) * LDM + tc] = bidx[i];
        }
        __syncthreads();
        if (t < BM) {
            float bs = Rs[t * LDM];
            int bi = Ri[t * LDM];
#pragma unroll
            for (int c = 1; c < 16; ++c) {
                const float sc = Rs[t * LDM + c];
                const int ii = Ri[t * LDM + c];
                if (sc < bs || (sc == bs && ii < bi)) { bs = sc; bi = ii; }
            }
            const int fi = rb * BM + t;
            if (fi < ns) {
                const unsigned long long pk =
                    ((unsigned long long)__float_as_uint(bs) << 32) | (unsigned)bi;
                atomicMin(&pack[frow[t]], pk);
            }
        }
    }
}

// gather z_q into out (fused fixdecode: pack overrides provisional idx);
// per-block diff2 partial via device atomicAdd; LAST block (ticket) computes
// the final scalars (max-range sum with min==0 provably, esq sum, loss/qq).
__global__ __launch_bounds__(256) void k_gather(const float* __restrict__ z,
                                                const float* __restrict__ emb,
                                                const int* __restrict__ idxbuf,
                                                const unsigned long long* __restrict__ pack,
                                                float* __restrict__ out,
                                                float* __restrict__ outidx,
                                                double* __restrict__ gsum,
                                                int* __restrict__ cnt,
                                                const float* __restrict__ esq,
                                                const unsigned* __restrict__ rmxg) {
    __shared__ double part[4];
    __shared__ int lastflag;
    const int row = blockIdx.x * 4 + (threadIdx.x >> 6);
    const int lane = threadIdx.x & 63;
    const unsigned long long p = pack[row];
    const int idx = (p != ~0ull) ? (int)(p & 0xffffffffu) : idxbuf[row];
    if (lane == 0) outidx[row] = (float)idx;
    const float4 e4 = *(const float4*)&emb[(size_t)idx * D + lane * 4];
    const float4 z4 = *(const float4*)&z[(size_t)row * D + lane * 4];
    *(float4*)&out[(size_t)row * D + lane * 4] = e4;
    const float dx = e4.x - z4.x, dy = e4.y - z4.y;
    const float dzv = e4.z - z4.z, dw = e4.w - z4.w;
    float s = dx * dx + dy * dy + dzv * dzv + dw * dw;
    s = waveReduceSumF(s);
    if (lane == 0) part[threadIdx.x >> 6] = (double)s;
    __syncthreads();
    if (threadIdx.x == 0) {
        atomicAdd(&gsum[0], part[0] + part[1] + part[2] + part[3]);
        __threadfence();
        const int tk = atomicAdd(&cnt[20], 1);
        lastflag = (tk == NGB - 1) ? 1 : 0;
    }
    __syncthreads();
    if (!lastflag) return;

    // ---- final reduction (all gsum adds visible: fence + ticket ordering) ----
    __shared__ double pm[4], pe[4];
    const int t = threadIdx.x;
    double m = 0.0, e2 = 0.0;
#pragma unroll
    for (int i = 0; i < NE / 256; ++i) {
        const int n = i * 256 + t;
        m += (double)sqrtf(__uint_as_float(rmxg[n]));
        e2 += (double)esq[n];
    }
    m = waveReduceSumD(m);
    e2 = waveReduceSumD(e2);
    if ((t & 63) == 0) { pm[t >> 6] = m; pe[t >> 6] = e2; }
    __syncthreads();
    if (t == 0) {
        const double diff2 = atomicAdd(&gsum[0], 0.0);   // coherent read
        const double msum = pm[0] + pm[1] + pm[2] + pm[3];
        const double esum = pe[0] + pe[1] + pe[2] + pe[3];
        const double loss = 1.25 * (diff2 / (double)((size_t)NZ * D));
        const double qq = 0.1 * (msum / (double)NE) + 0.1 * esum;
        out[(size_t)NZ * D + NZ] = (float)loss;
        out[(size_t)NZ * D + NZ + 1] = (float)qq;
    }
}

extern "C" void kernel_launch(void* const* d_in, const int* in_sizes, int n_in,
                              void* d_out, int out_size, void* d_ws, size_t ws_size,
                              hipStream_t stream) {
    const float* z = (const float*)d_in[0];
    const float* emb = (const float*)d_in[1];
    float* out = (float*)d_out;
    char* ws = (char*)d_ws;

    double* gsum = (double*)(ws + WS_SUMS);
    int* cnt = (int*)(ws + WS_CNT);
    float* zsq = (float*)(ws + WS_ZSQ);
    float* esq = (float*)(ws + WS_ESQ);
    int* idxb = (int*)(ws + WS_IDX);
    unsigned* kp1 = (unsigned*)(ws + WS_KP1);
    unsigned* kp2 = (unsigned*)(ws + WS_KP2);
    unsigned* rmx = (unsigned*)(ws + WS_RMX);
    unsigned long long* pack = (unsigned long long*)(ws + WS_PACK);
    int* lists = (int*)(ws + WS_LISTS);
    f16x8* zhf = (f16x8*)(ws + WS_ZHF);
    f16x8* ehf = (f16x8*)(ws + WS_EHF);
    unsigned long long* cand = (unsigned long long*)(ws + WS_CAND);
    float* outidx = out + (size_t)NZ * D;

    hipLaunchKernelGGL(k_cvt, dim3(NBLK_CVT), dim3(256), 0, stream,
                       z, emb, zhf, ehf, zsq, esq, cnt, rmx, pack, gsum);
    hipLaunchKernelGGL(k_big, dim3(NBLK_BIG), dim3(256), 0, stream,
                       zhf, ehf, esq, kp1, kp2, rmx);
    hipLaunchKernelGGL(k_merge, dim3(NZ / 256), dim3(256), 0, stream,
                       kp1, kp2, idxb, outidx, cnt, lists, cand);
    hipLaunchKernelGGL(k_fix, dim3(NBLK_FIX), dim3(256), 0, stream,
                       z, emb, zsq, esq, cnt, lists, cand, pack);
    hipLaunchKernelGGL(k_gather, dim3(NGB), dim3(256), 0, stream,
                       z, emb, idxb, pack, out, outidx, gsum, cnt, esq, rmx);
}

// Round 14
// 233.550 us; speedup vs baseline: 1.4958x; 1.4958x over previous
//
#include <hip/hip_runtime.h>

#define D 256
#define DA 288                     // augmented K (one extra 32-block)
#define NKB 9                      // DA/32
#define NKB_P 8                    // pairwise uses un-augmented 256
#define NE 8192
#define NZ 16384
#define BM 128
#define AM 256                     // argmin rows per block (4 waves x 64 rows)
#define BK 32
#define LDA (BM + 4)               // fp32 k-major LDS stride (fix_split role)
#define NB (NE / BM)
#define NTRI (NB * (NB + 1) / 2)
#define NSPLIT_A 16
#define SPLIT_NA (NE / NSPLIT_A)   // 512
#define GAPTH_A 0.4096f            // 1e-4 score units * 2^12 (acc units)
#define GAPTH_EFF 0.48f            // + 0.0625 trunc-quantization margin (10-bit key trunc)
#define LDM 17
#define NGB (NZ / 4)               // gather blocks = 4096
#define NCH_A (SPLIT_NA / 32)      // 16 chunks of 32 cols (argmin)
#define AUNITS (2 * NKB)           // 18 staging units per argmin chunk
#define PUNITS (2 * NKB_P)         // 16 staging units per pairwise chunk
#define NBLK_ARG (NZ / AM * NSPLIT_A)   // 1024 argmin-role blocks
#define NBLK_BIG (NBLK_ARG + NTRI)      // + 2080 pairwise-role blocks
#define NBLK_CVT (NZ / 64 + NE / 64 + 96)   // 256 z-cvt + 128 e-cvt + 96 pre
#define NBLK_FIX (1024 + 128)               // fix_split + fix_cand roles

// fp32-path LDS swizzle (verified R4-R11, fix_split role only)
#define SROT(kk) (8 * ((((kk) >> 2)) & 3))
#define SWZR(kk, r) ((((r) + SROT(kk)) & 127))

typedef _Float16 f16x8 __attribute__((ext_vector_type(8)));
typedef _Float16 f16x4 __attribute__((ext_vector_type(4)));
typedef float f32x4 __attribute__((ext_vector_type(4)));

#define MFMA16(a, b, c) __builtin_amdgcn_mfma_f32_16x16x32_f16(a, b, c, 0, 0, 0)

// async global->LDS, 16B/lane; LDS dest = uniform base + lane*16
__device__ __forceinline__ void g2l16(const void* g, void* lds) {
    __builtin_amdgcn_global_load_lds(
        (const __attribute__((address_space(1))) void*)g,
        (__attribute__((address_space(3))) void*)lds, 16, 0, 0);
}

__device__ __forceinline__ unsigned umax(unsigned a, unsigned b) { return a > b ? a : b; }
__device__ __forceinline__ unsigned umin(unsigned a, unsigned b) { return a < b ? a : b; }

// ---------------- workspace layout (bytes) ----------------
#define WS_SUMS   0                            // (unused, layout kept)
#define WS_CNT    64                           // int[32] (16 heavy lists + cand count @16)
#define WS_ZSQ    256                          // float[NZ]
#define WS_ESQ    (WS_ZSQ + NZ * 4)            // float[NE]
#define WS_IDX    (WS_ESQ + NE * 4)            // int[NZ]
#define WS_KP1    (WS_IDX + NZ * 4)            // u32 keys1 [NZ*16]
#define WS_KP2    (WS_KP1 + NZ * NSPLIT_A * 4) // u32 keys2 [NZ*16]
#define WS_RMX    (WS_KP2 + NZ * NSPLIT_A * 4) // uint[NE]
#define WS_RMN    (WS_RMX + NE * 4)            // (unused, layout kept)
#define WS_PACK   (WS_RMN + NE * 4)            // u64[NZ]
#define WS_GPART  (WS_PACK + NZ * 8)           // double[NGB]
#define WS_LISTS  (WS_GPART + NGB * 8)         // int[16][NZ]  (heavy fallback lists)
#define WS_ZHF    (WS_LISTS + NZ * NSPLIT_A * 4)   // frag-major f16 z
#define WS_EHF    (WS_ZHF + (size_t)(NZ / 16) * NKB * 64 * 8 * 2)
// candidate (row,col) pairs: reuse zhf region (dead after k_big)
#define WS_CAND   WS_ZHF

__device__ __forceinline__ float waveReduceSumF(float v) {
    v += __shfl_down(v, 32); v += __shfl_down(v, 16); v += __shfl_down(v, 8);
    v += __shfl_down(v, 4);  v += __shfl_down(v, 2);  v += __shfl_down(v, 1);
    return v;
}
__device__ __forceinline__ double waveReduceSumD(double v) {
    v += __shfl_down(v, 32); v += __shfl_down(v, 16); v += __shfl_down(v, 8);
    v += __shfl_down(v, 4);  v += __shfl_down(v, 2);  v += __shfl_down(v, 1);
    return v;
}

// np.sum(x*x) bit-exact for one 256-elem row (numpy pairwise summation)
__device__ __forceinline__ float rowsq256(const float* __restrict__ p) {
    float h[2];
#pragma unroll
    for (int half = 0; half < 2; ++half) {
        const float* q = p + half * 128;
        float4 a0 = *(const float4*)&q[0];
        float4 a1 = *(const float4*)&q[4];
        float r0 = __fmul_rn(a0.x, a0.x);
        float r1 = __fmul_rn(a0.y, a0.y);
        float r2 = __fmul_rn(a0.z, a0.z);
        float r3 = __fmul_rn(a0.w, a0.w);
        float r4 = __fmul_rn(a1.x, a1.x);
        float r5 = __fmul_rn(a1.y, a1.y);
        float r6 = __fmul_rn(a1.z, a1.z);
        float r7 = __fmul_rn(a1.w, a1.w);
#pragma unroll
        for (int i = 8; i < 128; i += 8) {
            const float4 b0 = *(const float4*)&q[i];
            const float4 b1 = *(const float4*)&q[i + 4];
            r0 = __fadd_rn(r0, __fmul_rn(b0.x, b0.x));
            r1 = __fadd_rn(r1, __fmul_rn(b0.y, b0.y));
            r2 = __fadd_rn(r2, __fmul_rn(b0.z, b0.z));
            r3 = __fadd_rn(r3, __fmul_rn(b0.w, b0.w));
            r4 = __fadd_rn(r4, __fmul_rn(b1.x, b1.x));
            r5 = __fadd_rn(r5, __fmul_rn(b1.y, b1.y));
            r6 = __fadd_rn(r6, __fmul_rn(b1.z, b1.z));
            r7 = __fadd_rn(r7, __fmul_rn(b1.w, b1.w));
        }
        const float t01 = __fadd_rn(r0, r1);
        const float t23 = __fadd_rn(r2, r3);
        const float t45 = __fadd_rn(r4, r5);
        const float t67 = __fadd_rn(r6, r7);
        h[half] = __fadd_rn(__fadd_rn(t01, t23), __fadd_rn(t45, t67));
    }
    return __fadd_rn(h[0], h[1]);
}

// ---- fused converter + pre kernel (contiguous role split) ----
// blocks [0,256): z transpose | [256,384): emb transpose (self-computed aug
// esq from the f32 values it loads; delta vs bit-exact ~1e-12, absorbed by
// f16 rounding + GAPTH margin) | [384,480): bit-exact rowsq + inits.
__global__ __launch_bounds__(256) void k_cvt(const float* __restrict__ z,
                                             const float* __restrict__ e,
                                             f16x8* __restrict__ zf,
                                             f16x8* __restrict__ ef,
                                             float* __restrict__ zsq,
                                             float* __restrict__ esq,
                                             int* __restrict__ cnt,
                                             unsigned* __restrict__ rmx,
                                             unsigned long long* __restrict__ pack) {
    __shared__ _Float16 Ls[64 * 296];
    __shared__ float Esq[64];
    const int t = threadIdx.x;
    const int bx = blockIdx.x;
    if (bx < NZ / 64) {
        const int row0 = bx * 64;
#pragma unroll
        for (int i = 0; i < 16; ++i) {
            const int f4 = i * 256 + t;
            const int r = f4 >> 6, c4 = f4 & 63;
            const float4 v = *(const float4*)&z[(size_t)(row0 + r) * D + c4 * 4];
            f16x4 h;
            h[0] = (_Float16)v.x; h[1] = (_Float16)v.y;
            h[2] = (_Float16)v.z; h[3] = (_Float16)v.w;
            *(f16x4*)&Ls[r * 296 + c4 * 4] = h;
        }
#pragma unroll
        for (int i = 0; i < 8; ++i) {
            const int idx = i * 256 + t;
            const int r = idx >> 5, c = idx & 31;
            Ls[r * 296 + 256 + c] = (c <= 1) ? (_Float16)1.0f : (_Float16)0.0f;
        }
        __syncthreads();
        const int l = t & 63, w = t >> 6;
#pragma unroll
        for (int kb = 0; kb < NKB; ++kb) {
            const f16x8 fr = *(const f16x8*)&Ls[(w * 16 + (l & 15)) * 296 + kb * 32 + (l >> 4) * 8];
            zf[((size_t)(bx * 4 + w) * NKB + kb) * 64 + l] = fr;
        }
    } else if (bx < NZ / 64 + NE / 64) {
        const int eb = bx - NZ / 64;
        const int row0 = eb * 64;
        // load + per-row sum-of-squares (wave w holds rows {i*4+w}, one
        // float4/lane); esq' error vs bit-exact ~1e-12 -> negligible in f16 aug
#pragma unroll
        for (int i = 0; i < 16; ++i) {
            const int f4 = i * 256 + t;
            const int r = f4 >> 6, c4 = f4 & 63;
            const float4 v = *(const float4*)&e[(size_t)(row0 + r) * D + c4 * 4];
            f16x4 h;
            h[0] = (_Float16)(v.x * 8192.0f); h[1] = (_Float16)(v.y * 8192.0f);
            h[2] = (_Float16)(v.z * 8192.0f); h[3] = (_Float16)(v.w * 8192.0f);
            *(f16x4*)&Ls[r * 296 + c4 * 4] = h;
            float d = v.x * v.x + v.y * v.y + v.z * v.z + v.w * v.w;
            d = waveReduceSumF(d);
            if ((t & 63) == 0) Esq[r] = d;
        }
        __syncthreads();
#pragma unroll
        for (int i = 0; i < 8; ++i) {
            const int idx = i * 256 + t;
            const int r = idx >> 5, c = idx & 31;
            _Float16 av = (_Float16)0.0f;
            if (c == 0) av = (_Float16)(Esq[r] * -4096.0f);
            if (c == 1) av = (_Float16)512.0f;
            Ls[r * 296 + 256 + c] = av;
        }
        __syncthreads();
        const int l = t & 63, w = t >> 6;
#pragma unroll
        for (int kb = 0; kb < NKB; ++kb) {
            const f16x8 fr = *(const f16x8*)&Ls[(w * 16 + (l & 15)) * 296 + kb * 32 + (l >> 4) * 8];
            ef[((size_t)(eb * 4 + w) * NKB + kb) * 64 + l] = fr;
        }
    } else {
        const int pb = bx - (NZ / 64 + NE / 64);   // 0..95
        if (pb == 0 && t < 24) cnt[t] = 0;
        if (pb < 64) {
            const int row = pb * 256 + t;
            zsq[row] = rowsq256(z + (size_t)row * D);
            pack[row] = ~0ull;
        } else {
            const int row = (pb - 64) * 256 + t;
            esq[row] = rowsq256(e + (size_t)row * D);
            rmx[row] = 0u;
        }
    }
}

// ---- fused MFMA kernel (R9-verified contiguous role split):
// blocks 0..1023 argmin, 1024..3103 pairwise (max-only; min_d==0 provably).
__global__ __launch_bounds__(256, 2) void k_big(
        const f16x8* __restrict__ zf, const f16x8* __restrict__ ef,
        const float* __restrict__ esq,
        unsigned* __restrict__ kp1, unsigned* __restrict__ kp2,
        unsigned* __restrict__ rmxg) {
    __shared__ __align__(16) char Sh[2 * AUNITS * 1024];   // 36864 B

    const int t = threadIdx.x;
    const int l = t & 63;
    const int w = t >> 6;
    const int quad = l >> 4;
    const int l15 = l & 15;

    if (blockIdx.x < NBLK_ARG) {
        // ================= argmin role (R7-verified body) =================
        _Float16 (*Bsm)[AUNITS * 512] = (_Float16(*)[AUNITS * 512])Sh;
        const int lin = blockIdx.x;
        const int rowblk = lin & 63;          // preserves (x=64, y=16) linearization
        const int sp = lin >> 6;
        const int row0 = rowblk * AM;
        const int arb0 = rowblk * 16 + w * 4;

        f16x8 ah[4][NKB];
#pragma unroll
        for (int mi = 0; mi < 4; ++mi)
#pragma unroll
            for (int kb = 0; kb < NKB; ++kb)
                ah[mi][kb] = zf[((size_t)(arb0 + mi) * NKB + kb) * 64 + l];

        unsigned b1[16], b2[16];
#pragma unroll
        for (int s = 0; s < 16; ++s) { b1[s] = 0u; b2[s] = 0u; }

        const char* gp[5];
#pragma unroll
        for (int ui = 0; ui < 5; ++ui) {
            const int u = w + ui * 4;
            const int uc = (u < AUNITS) ? u : 0;
            const int nj = uc / NKB, kb = uc - nj * NKB;
            gp[ui] = (const char*)&ef[((size_t)(sp * 32 + nj) * NKB + kb) * 64 + l];
        }

        auto stage = [&](size_t choff, int buf) {
            char* lb = (char*)&Bsm[0][0] + buf * (AUNITS * 1024);
#pragma unroll
            for (int ui = 0; ui < 5; ++ui) {
                const int u = w + ui * 4;
                if (u < AUNITS) g2l16(gp[ui] + choff, lb + u * 1024);
            }
        };

        auto ins = [&](unsigned key, int s) {
            unsigned b2n;
            asm("v_med3_u32 %0, %1, %2, %3"
                : "=v"(b2n) : "v"(key), "v"(b1[s]), "v"(b2[s]));
            b2[s] = b2n;
            b1[s] = umax(b1[s], key);
        };

        stage(0, 0);
        const f32x4 Zv = (f32x4){0.f, 0.f, 0.f, 0.f};
        int inv0 = 1023 - l15;
        for (int ch = 0; ch < NCH_A; ++ch) {
            const int buf = ch & 1;
            __syncthreads();
            if (ch + 1 < NCH_A) stage((size_t)(ch + 1) * 18432u, buf ^ 1);

            const unsigned invA = (unsigned)inv0;
            const unsigned invB = (unsigned)(inv0 - 16);

            f32x4 acc0[4], acc1[4];
            {
                const f16x8 bh = *(const f16x8*)&Bsm[buf][(0 * NKB + 0) * 512 + l * 8];
#pragma unroll
                for (int mi = 0; mi < 4; ++mi) acc0[mi] = MFMA16(ah[mi][0], bh, Zv);
            }
#pragma unroll
            for (int kb = 1; kb < NKB; ++kb) {
                const f16x8 bh = *(const f16x8*)&Bsm[buf][(0 * NKB + kb) * 512 + l * 8];
#pragma unroll
                for (int mi = 0; mi < 4; ++mi) acc0[mi] = MFMA16(ah[mi][kb], bh, acc0[mi]);
            }
            {
                const f16x8 bh = *(const f16x8*)&Bsm[buf][(1 * NKB + 0) * 512 + l * 8];
#pragma unroll
                for (int mi = 0; mi < 4; ++mi) acc1[mi] = MFMA16(ah[mi][0], bh, Zv);
            }
#pragma unroll
            for (int kb = 1; kb < NKB; ++kb) {
                const f16x8 bh = *(const f16x8*)&Bsm[buf][(1 * NKB + kb) * 512 + l * 8];
#pragma unroll
                for (int mi = 0; mi < 4; ++mi) acc1[mi] = MFMA16(ah[mi][kb], bh, acc1[mi]);
#pragma unroll
                for (int e = 2 * (kb - 1); e < 2 * (kb - 1) + 2; ++e) {
                    const int mi0 = e >> 2, r0 = e & 3;
                    ins((__float_as_uint(acc0[mi0][r0]) & 0xFFFFFC00u) | invA, e);
                }
            }
#pragma unroll
            for (int mi = 0; mi < 4; ++mi)
#pragma unroll
                for (int r = 0; r < 4; ++r)
                    ins((__float_as_uint(acc1[mi][r]) & 0xFFFFFC00u) | invB, mi * 4 + r);

            inv0 -= 32;
        }

#pragma unroll
        for (int s = 0; s < 16; ++s) {
            unsigned v1 = b1[s], v2 = b2[s];
#pragma unroll
            for (int m = 1; m <= 8; m <<= 1) {
                const unsigned o1 = __shfl_xor(v1, m);
                const unsigned o2 = __shfl_xor(v2, m);
                const unsigned n2 = umax(umin(v1, o1), umax(v2, o2));
                v1 = umax(v1, o1);
                v2 = n2;
            }
            if (l15 == 0) {
                const int mi = s >> 2, r = s & 3;
                const int row = row0 + w * 64 + mi * 16 + quad * 4 + r;
                kp1[(size_t)row * NSPLIT_A + sp] = v1;
                kp2[(size_t)row * NSPLIT_A + sp] = v2;
            }
        }
    } else {
        // ================= pairwise role (max-only) =================
        _Float16 (*Bsm)[PUNITS * 512] = (_Float16(*)[PUNITS * 512])Sh;
        int p = blockIdx.x - NBLK_ARG;
        int bi = 0;
        while (p >= NB - bi) { p -= NB - bi; ++bi; }
        const int bj = bi + p;
        const int row0 = bi * BM;
        const int c0 = bj * BM;

        float sR[8], sC[8];
#pragma unroll
        for (int mi = 0; mi < 2; ++mi)
#pragma unroll
            for (int r = 0; r < 4; ++r)
                sR[mi * 4 + r] = esq[row0 + w * 32 + mi * 16 + quad * 4 + r];
#pragma unroll
        for (int nj = 0; nj < 8; ++nj) sC[nj] = esq[c0 + nj * 16 + l15];

        const int arb = bi * 8 + w * 2;
        const int cfb = bj * 8;

        f16x8 ah[2][NKB_P];
#pragma unroll
        for (int kb = 0; kb < NKB_P; ++kb) {
            ah[0][kb] = ef[((size_t)arb * NKB + kb) * 64 + l];
            ah[1][kb] = ef[((size_t)(arb + 1) * NKB + kb) * 64 + l];
        }

        float rmx[8], cmx[8];
#pragma unroll
        for (int s = 0; s < 8; ++s) { rmx[s] = 0.f; cmx[s] = 0.f; }

        auto stage = [&](int ch, int buf) {
            for (int u = w; u < PUNITS; u += 4) {
                const int nj = u >> 3, kb = u & 7;
                g2l16(&ef[((size_t)(cfb + ch * 2 + nj) * NKB + kb) * 64 + l],
                      &Bsm[buf][u * 512]);
            }
        };

        stage(0, 0);
        for (int ch = 0; ch < 4; ++ch) {            // 4 chunks x 32 cols = 128
            const int buf = ch & 1;
            __syncthreads();
            if (ch + 1 < 4) stage(ch + 1, buf ^ 1);

            f32x4 acc[2][2];
#pragma unroll
            for (int mi = 0; mi < 2; ++mi)
#pragma unroll
                for (int nj = 0; nj < 2; ++nj) acc[mi][nj] = (f32x4){0.f, 0.f, 0.f, 0.f};

#pragma unroll
            for (int kb = 0; kb < NKB_P; ++kb) {
                const f16x8 bh0 = *(const f16x8*)&Bsm[buf][(0 * 8 + kb) * 512 + l * 8];
                const f16x8 bh1 = *(const f16x8*)&Bsm[buf][(1 * 8 + kb) * 512 + l * 8];
#pragma unroll
                for (int mi = 0; mi < 2; ++mi) {
                    acc[mi][0] = MFMA16(ah[mi][kb], bh0, acc[mi][0]);
                    acc[mi][1] = MFMA16(ah[mi][kb], bh1, acc[mi][1]);
                }
            }

#pragma unroll
            for (int nj = 0; nj < 2; ++nj) {
                const int cidx = ch * 2 + nj;
#pragma unroll
                for (int mi = 0; mi < 2; ++mi)
#pragma unroll
                    for (int r = 0; r < 4; ++r) {
                        const int s = mi * 4 + r;
                        const float t1 = __fadd_rn(sR[s], sC[cidx]);
                        const float d2 = fmaf(-0x1p-25f, acc[mi][nj][r], t1);
                        const float d2c = fmaxf(d2, 0.f);
                        rmx[s] = fmaxf(rmx[s], d2c);
                        cmx[cidx] = fmaxf(cmx[cidx], d2c);
                    }
            }
        }

        // rows: butterfly across the 16 lanes of the quad group, then atomics
#pragma unroll
        for (int s = 0; s < 8; ++s) {
#pragma unroll
            for (int m = 1; m <= 8; m <<= 1)
                rmx[s] = fmaxf(rmx[s], __shfl_xor(rmx[s], m));
        }
        if (l15 == 0) {
#pragma unroll
            for (int s = 0; s < 8; ++s) {
                const int mi = s >> 2, r = s & 3;
                const int row = row0 + w * 32 + mi * 16 + quad * 4 + r;
                atomicMax(&rmxg[row], __float_as_uint(rmx[s]));
            }
        }

        // cols: butterfly across quads, LDS across waves (reuse Bsm), then atomics
#pragma unroll
        for (int nj = 0; nj < 8; ++nj) {
#pragma unroll
            for (int m = 16; m <= 32; m <<= 1)
                cmx[nj] = fmaxf(cmx[nj], __shfl_xor(cmx[nj], m));
        }
        __syncthreads();   // all chunk reads done; Bsm reusable
        float* Mx = (float*)&Bsm[0][0];          // [4][128]
        if (quad == 0) {
#pragma unroll
            for (int nj = 0; nj < 8; ++nj)
                Mx[w * 128 + nj * 16 + l15] = cmx[nj];
        }
        __syncthreads();
        if (t < BM) {
            float mx = Mx[t];
#pragma unroll
            for (int ww = 1; ww < 4; ++ww)
                mx = fmaxf(mx, Mx[ww * 128 + t]);
            atomicMax(&rmxg[c0 + t], __float_as_uint(mx));
        }
    }
}

// merge split keys; provisional idx; emit per-split top-1 candidates for
// near-tie rows; full-split fallback only when a split's SECOND-best is also
// in range.
__global__ __launch_bounds__(256) void k_merge(const unsigned* __restrict__ kp1,
                                               const unsigned* __restrict__ kp2,
                                               int* __restrict__ idxbuf,
                                               float* __restrict__ outidx,
                                               int* __restrict__ cnt,
                                               int* __restrict__ lists,
                                               unsigned long long* __restrict__ cand) {
    const int n = blockIdx.x * 256 + threadIdx.x;
    unsigned k1v[NSPLIT_A], k2v[NSPLIT_A];
#pragma unroll
    for (int s = 0; s < NSPLIT_A; ++s) {
        k1v[s] = kp1[n * NSPLIT_A + s];
        k2v[s] = kp2[n * NSPLIT_A + s];
    }
    unsigned K1 = k1v[0]; int sb = 0;
#pragma unroll
    for (int s = 1; s < NSPLIT_A; ++s)
        if (k1v[s] > K1) { K1 = k1v[s]; sb = s; }
    unsigned K2 = 0u;
#pragma unroll
    for (int s = 0; s < NSPLIT_A; ++s) {
        const unsigned a = (s == sb) ? k2v[s] : k1v[s];
        K2 = umax(K2, a);
    }
    const int ii1 = sb * SPLIT_NA + 1023 - (int)(K1 & 1023u);
    idxbuf[n] = ii1;
    outidx[n] = (float)ii1;
    const float val1 = __uint_as_float(K1 & 0xFFFFFC00u);
    const float val2 = __uint_as_float(K2 & 0xFFFFFC00u);
    if (val1 - val2 < GAPTH_EFF) {
        const float vlim = val1 - GAPTH_EFF;    // qualify: val >= vlim
        int ncand = 0;
#pragma unroll
        for (int s = 0; s < NSPLIT_A; ++s) {
            if (__uint_as_float(k1v[s] & 0xFFFFFC00u) >= vlim) ++ncand;
            if (__uint_as_float(k2v[s] & 0xFFFFFC00u) >= vlim) {
                const int p = atomicAdd(&cnt[s], 1);
                lists[s * NZ + p] = n;
            }
        }
        const int base = atomicAdd(&cnt[16], ncand);
        int o = 0;
#pragma unroll
        for (int s = 0; s < NSPLIT_A; ++s)
            if (__uint_as_float(k1v[s] & 0xFFFFFC00u) >= vlim) {
                const int col = s * SPLIT_NA + 1023 - (int)(k1v[s] & 1023u);
                cand[base + o] = ((unsigned long long)(unsigned)n << 32) |
                                 (unsigned)col;
                ++o;
            }
    }
}

// ---- fused fp32 repair: blocks [0,1024) = fix_split role (np-bit-exact,
// exact (s,chunk,rb) mapping of the former 2D grid: x=bx&63, y=bx>>6);
// blocks [1024,1152) = fix_cand role (bit-identical fmaf chain).
__global__ __launch_bounds__(256) void k_fix(const float* __restrict__ z,
                                             const float* __restrict__ emb,
                                             const float* __restrict__ zsq,
                                             const float* __restrict__ esq,
                                             const int* __restrict__ cnt,
                                             const int* __restrict__ lists,
                                             const unsigned long long* __restrict__ cand,
                                             unsigned long long* __restrict__ pack) {
    __shared__ float As[BK * LDA];
    __shared__ float Bs[BK * LDA];
    __shared__ float Sq[BM];
    __shared__ int frow[BM];

    const int t = threadIdx.x;
    if (blockIdx.x >= 1024) {
        // ================= fix_cand role =================
        const int nc = cnt[16];
        for (int i = (blockIdx.x - 1024) * 256 + t; i < nc; i += 128 * 256) {
            const unsigned long long pr = cand[i];
            const int row = (int)(pr >> 32);
            const int col = (int)(pr & 0xffffffffu);
            const float4* zp = (const float4*)(z + (size_t)row * D);
            const float4* ep = (const float4*)(emb + (size_t)col * D);
            float acc = 0.f;
#pragma unroll
            for (int k4 = 0; k4 < D / 4; ++k4) {
                const float4 a = zp[k4];
                const float4 b = ep[k4];
                acc = fmaf(a.x, b.x, acc);
                acc = fmaf(a.y, b.y, acc);
                acc = fmaf(a.z, b.z, acc);
                acc = fmaf(a.w, b.w, acc);
            }
            const float sc = fmaf(-2.f, acc, __fadd_rn(zsq[row], esq[col]));
            const unsigned long long pk =
                ((unsigned long long)__float_as_uint(sc) << 32) | (unsigned)col;
            atomicMin(&pack[row], pk);
        }
        return;
    }

    // ================= fix_split role =================
    const int bx = blockIdx.x;
    const int xl = bx & 63;
    const int s = xl >> 2;
    const int chunk = xl & 3;
    const int ns = cnt[s];
    const int c0 = s * SPLIT_NA + chunk * BM;
    const int tr = t >> 4;
    const int tc = t & 15;
    const int sr = t >> 3;
    const int skq = t & 7;
    const int wrot = 8 * (skq & 3);

    for (int rb = bx >> 6; rb * BM < ns; rb += 16) {
        __syncthreads();
        if (t < BM) {
            const int fi = rb * BM + t;
            frow[t] = (fi < ns) ? lists[s * NZ + fi] : lists[s * NZ];
            Sq[t] = esq[c0 + t];
        }
        __syncthreads();

        float zqr[8];
#pragma unroll
        for (int i = 0; i < 8; ++i) zqr[i] = zsq[frow[tr * 8 + i]];

        float best[8];
        int bidx[8];
#pragma unroll
        for (int i = 0; i < 8; ++i) { best[i] = 3.4e38f; bidx[i] = 0; }

        float acc[8][8];
#pragma unroll
        for (int i = 0; i < 8; ++i)
#pragma unroll
            for (int j = 0; j < 8; ++j) acc[i][j] = 0.f;

        float4 pav[4], pbv[4];
#pragma unroll
        for (int q = 0; q < 4; ++q) {
            const int r = sr + 32 * q;
            pav[q] = *(const float4*)&z[(size_t)frow[r] * D + 0 + 4 * skq];
            pbv[q] = *(const float4*)&emb[(size_t)(c0 + r) * D + 0 + 4 * skq];
        }

        for (int kb = 0; kb < D; kb += BK) {
            __syncthreads();
#pragma unroll
            for (int q = 0; q < 4; ++q) {
                const int r = sr + 32 * q;
                const int rr = (r + wrot) & 127;
                As[(4 * skq + 0) * LDA + rr] = pav[q].x;
                As[(4 * skq + 1) * LDA + rr] = pav[q].y;
                As[(4 * skq + 2) * LDA + rr] = pav[q].z;
                As[(4 * skq + 3) * LDA + rr] = pav[q].w;
                Bs[(4 * skq + 0) * LDA + rr] = pbv[q].x;
                Bs[(4 * skq + 1) * LDA + rr] = pbv[q].y;
                Bs[(4 * skq + 2) * LDA + rr] = pbv[q].z;
                Bs[(4 * skq + 3) * LDA + rr] = pbv[q].w;
            }
            __syncthreads();
            if (kb + BK < D) {
#pragma unroll
                for (int q = 0; q < 4; ++q) {
                    const int r = sr + 32 * q;
                    pav[q] = *(const float4*)&z[(size_t)frow[r] * D + kb + BK + 4 * skq];
                    pbv[q] = *(const float4*)&emb[(size_t)(c0 + r) * D + kb + BK + 4 * skq];
                }
            }
#pragma unroll
            for (int k = 0; k < BK; ++k) {
                const float4 a0 = *(const float4*)&As[k * LDA + SWZR(k, tr * 8)];
                const float4 a1 = *(const float4*)&As[k * LDA + SWZR(k, tr * 8 + 4)];
                const float4 b0 = *(const float4*)&Bs[k * LDA + SWZR(k, tc * 4)];
                const float4 b1 = *(const float4*)&Bs[k * LDA + SWZR(k, 64 + tc * 4)];
                const float a[8] = {a0.x, a0.y, a0.z, a0.w, a1.x, a1.y, a1.z, a1.w};
                const float b[8] = {b0.x, b0.y, b0.z, b0.w, b1.x, b1.y, b1.z, b1.w};
#pragma unroll
                for (int i = 0; i < 8; ++i)
#pragma unroll
                    for (int j = 0; j < 8; ++j)
                        acc[i][j] = fmaf(a[i], b[j], acc[i][j]);
            }
        }
#pragma unroll
        for (int jj = 0; jj < 8; ++jj) {
            const int cloc = (jj < 4) ? (tc * 4 + jj) : (64 + tc * 4 + (jj - 4));
            const float sq = Sq[cloc];
            const int gcol = c0 + cloc;
#pragma unroll
            for (int i = 0; i < 8; ++i) {
                const float t1 = __fadd_rn(zqr[i], sq);
                const float sc = fmaf(-2.f, acc[i][jj], t1);
                if (sc < best[i]) { best[i] = sc; bidx[i] = gcol; }
            }
        }
        __syncthreads();

        float* Rs = As;
        int* Ri = (int*)Bs;
#pragma unroll
        for (int i = 0; i < 8; ++i) {
            Rs[(tr * 8 + i) * LDM + tc] = best[i];
            Ri[(tr * 8 + i) * LDM + tc] = bidx[i];
        }
        __syncthreads();
        if (t < BM) {
            float bs = Rs[t * LDM];
            int bi = Ri[t * LDM];
#pragma unroll
            for (int c = 1; c < 16; ++c) {
                const float sc = Rs[t * LDM + c];
                const int ii = Ri[t * LDM + c];
                if (sc < bs || (sc == bs && ii < bi)) { bs = sc; bi = ii; }
            }
            const int fi = rb * BM + t;
            if (fi < ns) {
                const unsigned long long pk =
                    ((unsigned long long)__float_as_uint(bs) << 32) | (unsigned)bi;
                atomicMin(&pack[frow[t]], pk);
            }
        }
    }
}

// gather z_q into out (fused fixdecode: pack overrides provisional idx);
// per-block partial of sum((z_q-z)^2) -> gpart (NO atomics)
__global__ __launch_bounds__(256) void k_gather(const float* __restrict__ z,
                                                const float* __restrict__ emb,
                                                const int* __restrict__ idxbuf,
                                                const unsigned long long* __restrict__ pack,
                                                float* __restrict__ out,
                                                float* __restrict__ outidx,
                                                double* __restrict__ gpart) {
    __shared__ double part[4];
    const int row = blockIdx.x * 4 + (threadIdx.x >> 6);
    const int lane = threadIdx.x & 63;
    const unsigned long long p = pack[row];
    const int idx = (p != ~0ull) ? (int)(p & 0xffffffffu) : idxbuf[row];
    if (lane == 0) outidx[row] = (float)idx;
    const float4 e4 = *(const float4*)&emb[(size_t)idx * D + lane * 4];
    const float4 z4 = *(const float4*)&z[(size_t)row * D + lane * 4];
    *(float4*)&out[(size_t)row * D + lane * 4] = e4;
    const float dx = e4.x - z4.x, dy = e4.y - z4.y;
    const float dzv = e4.z - z4.z, dw = e4.w - z4.w;
    float s = dx * dx + dy * dy + dzv * dzv + dw * dw;
    s = waveReduceSumF(s);
    if (lane == 0) part[threadIdx.x >> 6] = (double)s;
    __syncthreads();
    if (threadIdx.x == 0)
        gpart[blockIdx.x] = part[0] + part[1] + part[2] + part[3];
}

// final reduce: gather-partials + max-range sum (min==0 provably) + esq sum
__global__ __launch_bounds__(256) void k_final(const double* __restrict__ gpart,
                                               const float* __restrict__ esq,
                                               const unsigned* __restrict__ rmxg,
                                               float* __restrict__ out) {
    __shared__ double part[4];
    __shared__ double partm[4];
    __shared__ double parte[4];
    const int t = threadIdx.x;
    double s = 0.0;
#pragma unroll
    for (int i = 0; i < NGB / 256; ++i) s += gpart[i * 256 + t];
    s = waveReduceSumD(s);
    double m = 0.0, e2 = 0.0;
#pragma unroll
    for (int i = 0; i < NE / 256; ++i) {
        const int n = i * 256 + t;
        m += (double)sqrtf(__uint_as_float(rmxg[n]));
        e2 += (double)esq[n];
    }
    m = waveReduceSumD(m);
    e2 = waveReduceSumD(e2);
    if ((t & 63) == 0) { part[t >> 6] = s; partm[t >> 6] = m; parte[t >> 6] = e2; }
    __syncthreads();
    if (t == 0) {
        const double diff2 = part[0] + part[1] + part[2] + part[3];
        const double msum = partm[0] + partm[1] + partm[2] + partm[3];
        const double esum = parte[0] + parte[1] + parte[2] + parte[3];
        const double loss = 1.25 * (diff2 / (double)((size_t)NZ * D));
        const double qq = 0.1 * (msum / (double)NE) + 0.1 * esum;
        out[(size_t)NZ * D + NZ] = (float)loss;
        out[(size_t)NZ * D + NZ + 1] = (float)qq;
    }
}

extern "C" void kernel_launch(void* const* d_in, const int* in_sizes, int n_in,
                              void* d_out, int out_size, void* d_ws, size_t ws_size,
                              hipStream_t stream) {
    const float* z = (const float*)d_in[0];
    const float* emb = (const float*)d_in[1];
    float* out = (float*)d_out;
    char* ws = (char*)d_ws;

    int* cnt = (int*)(ws + WS_CNT);
    float* zsq = (float*)(ws + WS_ZSQ);
    float* esq = (float*)(ws + WS_ESQ);
    int* idxb = (int*)(ws + WS_IDX);
    unsigned* kp1 = (unsigned*)(ws + WS_KP1);
    unsigned* kp2 = (unsigned*)(ws + WS_KP2);
    unsigned* rmx = (unsigned*)(ws + WS_RMX);
    unsigned long long* pack = (unsigned long long*)(ws + WS_PACK);
    double* gpart = (double*)(ws + WS_GPART);
    int* lists = (int*)(ws + WS_LISTS);
    f16x8* zhf = (f16x8*)(ws + WS_ZHF);
    f16x8* ehf = (f16x8*)(ws + WS_EHF);
    unsigned long long* cand = (unsigned long long*)(ws + WS_CAND);
    float* outidx = out + (size_t)NZ * D;

    hipLaunchKernelGGL(k_cvt, dim3(NBLK_CVT), dim3(256), 0, stream,
                       z, emb, zhf, ehf, zsq, esq, cnt, rmx, pack);
    hipLaunchKernelGGL(k_big, dim3(NBLK_BIG), dim3(256), 0, stream,
                       zhf, ehf, esq, kp1, kp2, rmx);
    hipLaunchKernelGGL(k_merge, dim3(NZ / 256), dim3(256), 0, stream,
                       kp1, kp2, idxb, outidx, cnt, lists, cand);
    hipLaunchKernelGGL(k_fix, dim3(NBLK_FIX), dim3(256), 0, stream,
                       z, emb, zsq, esq, cnt, lists, cand, pack);
    hipLaunchKernelGGL(k_gather, dim3(NGB), dim3(256), 0, stream,
                       z, emb, idxb, pack, out, outidx, gpart);
    hipLaunchKernelGGL(k_final, dim3(1), dim3(256), 0, stream,
                       gpart, esq, rmx, out);
}

// Round 15
// 230.654 us; speedup vs baseline: 1.5146x; 1.0126x over previous
//
#include <hip/hip_runtime.h>

#define D 256
#define DA 288                     // augmented K (one extra 32-block)
#define NKB 9                      // DA/32
#define NKB_P 8                    // pairwise uses un-augmented 256
#define NE 8192
#define NZ 16384
#define BM 128
#define AM 256                     // argmin rows per block (4 waves x 64 rows)
#define BK 32
#define LDA (BM + 4)               // fp32 k-major LDS stride (fix_split role)
#define NB (NE / BM)
#define NTRI (NB * (NB + 1) / 2)
#define NSPLIT_A 16
#define SPLIT_NA (NE / NSPLIT_A)   // 512
#define GAPTH_A 0.4096f            // 1e-4 score units * 2^12 (acc units)
#define GAPTH_EFF 0.48f            // + 0.0625 trunc-quantization margin (10-bit key trunc)
#define LDM 17
#define NGB (NZ / 4)               // gather blocks = 4096
#define NCH_A (SPLIT_NA / 32)      // 16 chunks of 32 cols (argmin)
#define AUNITS (2 * NKB)           // 18 staging units per argmin chunk
#define PUNITS (2 * NKB_P)         // 16 staging units per pairwise chunk
#define NBLK_ARG (NZ / AM * NSPLIT_A)   // 1024 argmin-role blocks
#define NBLK_BIG (NBLK_ARG + NTRI)      // + 2080 pairwise-role blocks
#define NBLK_CVT (NZ / 64 + NE / 64 + 96)   // 256 z-cvt + 128 e-cvt + 96 pre
#define NBLK_FIX (1024 + 128)               // fix_split + fix_cand roles

// fp32-path LDS swizzle (verified R4-R11, fix_split role only)
#define SROT(kk) (8 * ((((kk) >> 2)) & 3))
#define SWZR(kk, r) ((((r) + SROT(kk)) & 127))

typedef _Float16 f16x8 __attribute__((ext_vector_type(8)));
typedef _Float16 f16x4 __attribute__((ext_vector_type(4)));
typedef float f32x4 __attribute__((ext_vector_type(4)));

#define MFMA16(a, b, c) __builtin_amdgcn_mfma_f32_16x16x32_f16(a, b, c, 0, 0, 0)

// async global->LDS, 16B/lane; LDS dest = uniform base + lane*16
__device__ __forceinline__ void g2l16(const void* g, void* lds) {
    __builtin_amdgcn_global_load_lds(
        (const __attribute__((address_space(1))) void*)g,
        (__attribute__((address_space(3))) void*)lds, 16, 0, 0);
}

__device__ __forceinline__ unsigned umax(unsigned a, unsigned b) { return a > b ? a : b; }
__device__ __forceinline__ unsigned umin(unsigned a, unsigned b) { return a < b ? a : b; }

// ---------------- workspace layout (bytes) ----------------
#define WS_SUMS   0                            // (unused, layout kept)
#define WS_CNT    64                           // int[32] (16 heavy lists + cand count @16)
#define WS_ZSQ    256                          // float[NZ]
#define WS_ESQ    (WS_ZSQ + NZ * 4)            // float[NE]
#define WS_IDX    (WS_ESQ + NE * 4)            // int[NZ]
#define WS_KP1    (WS_IDX + NZ * 4)            // u32 keys1 [NSPLIT][NZ] (transposed)
#define WS_KP2    (WS_KP1 + NZ * NSPLIT_A * 4) // u32 keys2 [NSPLIT][NZ]
#define WS_RMX    (WS_KP2 + NZ * NSPLIT_A * 4) // uint[NE]
#define WS_RMN    (WS_RMX + NE * 4)            // (unused, layout kept)
#define WS_PACK   (WS_RMN + NE * 4)            // u64[NZ]
#define WS_GPART  (WS_PACK + NZ * 8)           // double[NGB]
#define WS_LISTS  (WS_GPART + NGB * 8)         // int[16][NZ]  (heavy fallback lists)
#define WS_ZHF    (WS_LISTS + NZ * NSPLIT_A * 4)   // frag-major f16 z
#define WS_EHF    (WS_ZHF + (size_t)(NZ / 16) * NKB * 64 * 8 * 2)
// candidate (row,col) pairs: reuse zhf region (dead after k_big)
#define WS_CAND   WS_ZHF

__device__ __forceinline__ float waveReduceSumF(float v) {
    v += __shfl_down(v, 32); v += __shfl_down(v, 16); v += __shfl_down(v, 8);
    v += __shfl_down(v, 4);  v += __shfl_down(v, 2);  v += __shfl_down(v, 1);
    return v;
}
__device__ __forceinline__ double waveReduceSumD(double v) {
    v += __shfl_down(v, 32); v += __shfl_down(v, 16); v += __shfl_down(v, 8);
    v += __shfl_down(v, 4);  v += __shfl_down(v, 2);  v += __shfl_down(v, 1);
    return v;
}

// np.sum(x*x) bit-exact for one 256-elem row (numpy pairwise summation)
__device__ __forceinline__ float rowsq256(const float* __restrict__ p) {
    float h[2];
#pragma unroll
    for (int half = 0; half < 2; ++half) {
        const float* q = p + half * 128;
        float4 a0 = *(const float4*)&q[0];
        float4 a1 = *(const float4*)&q[4];
        float r0 = __fmul_rn(a0.x, a0.x);
        float r1 = __fmul_rn(a0.y, a0.y);
        float r2 = __fmul_rn(a0.z, a0.z);
        float r3 = __fmul_rn(a0.w, a0.w);
        float r4 = __fmul_rn(a1.x, a1.x);
        float r5 = __fmul_rn(a1.y, a1.y);
        float r6 = __fmul_rn(a1.z, a1.z);
        float r7 = __fmul_rn(a1.w, a1.w);
#pragma unroll
        for (int i = 8; i < 128; i += 8) {
            const float4 b0 = *(const float4*)&q[i];
            const float4 b1 = *(const float4*)&q[i + 4];
            r0 = __fadd_rn(r0, __fmul_rn(b0.x, b0.x));
            r1 = __fadd_rn(r1, __fmul_rn(b0.y, b0.y));
            r2 = __fadd_rn(r2, __fmul_rn(b0.z, b0.z));
            r3 = __fadd_rn(r3, __fmul_rn(b0.w, b0.w));
            r4 = __fadd_rn(r4, __fmul_rn(b1.x, b1.x));
            r5 = __fadd_rn(r5, __fmul_rn(b1.y, b1.y));
            r6 = __fadd_rn(r6, __fmul_rn(b1.z, b1.z));
            r7 = __fadd_rn(r7, __fmul_rn(b1.w, b1.w));
        }
        const float t01 = __fadd_rn(r0, r1);
        const float t23 = __fadd_rn(r2, r3);
        const float t45 = __fadd_rn(r4, r5);
        const float t67 = __fadd_rn(r6, r7);
        h[half] = __fadd_rn(__fadd_rn(t01, t23), __fadd_rn(t45, t67));
    }
    return __fadd_rn(h[0], h[1]);
}

// ---- fused converter + pre kernel (contiguous role split) ----
// blocks [0,256): z transpose | [256,384): emb transpose (self-computed aug
// esq from the f32 values it loads; delta vs bit-exact ~1e-12, absorbed by
// f16 rounding + GAPTH margin) | [384,480): bit-exact rowsq + inits.
__global__ __launch_bounds__(256) void k_cvt(const float* __restrict__ z,
                                             const float* __restrict__ e,
                                             f16x8* __restrict__ zf,
                                             f16x8* __restrict__ ef,
                                             float* __restrict__ zsq,
                                             float* __restrict__ esq,
                                             int* __restrict__ cnt,
                                             unsigned* __restrict__ rmx,
                                             unsigned long long* __restrict__ pack) {
    __shared__ _Float16 Ls[64 * 296];
    __shared__ float Esq[64];
    const int t = threadIdx.x;
    const int bx = blockIdx.x;
    if (bx < NZ / 64) {
        const int row0 = bx * 64;
#pragma unroll
        for (int i = 0; i < 16; ++i) {
            const int f4 = i * 256 + t;
            const int r = f4 >> 6, c4 = f4 & 63;
            const float4 v = *(const float4*)&z[(size_t)(row0 + r) * D + c4 * 4];
            f16x4 h;
            h[0] = (_Float16)v.x; h[1] = (_Float16)v.y;
            h[2] = (_Float16)v.z; h[3] = (_Float16)v.w;
            *(f16x4*)&Ls[r * 296 + c4 * 4] = h;
        }
#pragma unroll
        for (int i = 0; i < 8; ++i) {
            const int idx = i * 256 + t;
            const int r = idx >> 5, c = idx & 31;
            Ls[r * 296 + 256 + c] = (c <= 1) ? (_Float16)1.0f : (_Float16)0.0f;
        }
        __syncthreads();
        const int l = t & 63, w = t >> 6;
#pragma unroll
        for (int kb = 0; kb < NKB; ++kb) {
            const f16x8 fr = *(const f16x8*)&Ls[(w * 16 + (l & 15)) * 296 + kb * 32 + (l >> 4) * 8];
            zf[((size_t)(bx * 4 + w) * NKB + kb) * 64 + l] = fr;
        }
    } else if (bx < NZ / 64 + NE / 64) {
        const int eb = bx - NZ / 64;
        const int row0 = eb * 64;
        // load + per-row sum-of-squares (wave w holds rows {i*4+w}, one
        // float4/lane); esq' error vs bit-exact ~1e-12 -> negligible in f16 aug
#pragma unroll
        for (int i = 0; i < 16; ++i) {
            const int f4 = i * 256 + t;
            const int r = f4 >> 6, c4 = f4 & 63;
            const float4 v = *(const float4*)&e[(size_t)(row0 + r) * D + c4 * 4];
            f16x4 h;
            h[0] = (_Float16)(v.x * 8192.0f); h[1] = (_Float16)(v.y * 8192.0f);
            h[2] = (_Float16)(v.z * 8192.0f); h[3] = (_Float16)(v.w * 8192.0f);
            *(f16x4*)&Ls[r * 296 + c4 * 4] = h;
            float d = v.x * v.x + v.y * v.y + v.z * v.z + v.w * v.w;
            d = waveReduceSumF(d);
            if ((t & 63) == 0) Esq[r] = d;
        }
        __syncthreads();
#pragma unroll
        for (int i = 0; i < 8; ++i) {
            const int idx = i * 256 + t;
            const int r = idx >> 5, c = idx & 31;
            _Float16 av = (_Float16)0.0f;
            if (c == 0) av = (_Float16)(Esq[r] * -4096.0f);
            if (c == 1) av = (_Float16)512.0f;
            Ls[r * 296 + 256 + c] = av;
        }
        __syncthreads();
        const int l = t & 63, w = t >> 6;
#pragma unroll
        for (int kb = 0; kb < NKB; ++kb) {
            const f16x8 fr = *(const f16x8*)&Ls[(w * 16 + (l & 15)) * 296 + kb * 32 + (l >> 4) * 8];
            ef[((size_t)(eb * 4 + w) * NKB + kb) * 64 + l] = fr;
        }
    } else {
        const int pb = bx - (NZ / 64 + NE / 64);   // 0..95
        if (pb == 0 && t < 24) cnt[t] = 0;
        if (pb < 64) {
            const int row = pb * 256 + t;
            zsq[row] = rowsq256(z + (size_t)row * D);
            pack[row] = ~0ull;
        } else {
            const int row = (pb - 64) * 256 + t;
            esq[row] = rowsq256(e + (size_t)row * D);
            rmx[row] = 0u;
        }
    }
}

// ---- fused MFMA kernel (R9-verified contiguous role split):
// blocks 0..1023 argmin, 1024..3103 pairwise (max-only; min_d==0 provably).
// kp output layout: [sp][row] (transposed) for coalesced k_merge reads.
__global__ __launch_bounds__(256, 2) void k_big(
        const f16x8* __restrict__ zf, const f16x8* __restrict__ ef,
        const float* __restrict__ esq,
        unsigned* __restrict__ kp1, unsigned* __restrict__ kp2,
        unsigned* __restrict__ rmxg) {
    __shared__ __align__(16) char Sh[2 * AUNITS * 1024];   // 36864 B

    const int t = threadIdx.x;
    const int l = t & 63;
    const int w = t >> 6;
    const int quad = l >> 4;
    const int l15 = l & 15;

    if (blockIdx.x < NBLK_ARG) {
        // ================= argmin role (R7-verified body) =================
        _Float16 (*Bsm)[AUNITS * 512] = (_Float16(*)[AUNITS * 512])Sh;
        const int lin = blockIdx.x;
        const int rowblk = lin & 63;          // preserves (x=64, y=16) linearization
        const int sp = lin >> 6;
        const int row0 = rowblk * AM;
        const int arb0 = rowblk * 16 + w * 4;

        f16x8 ah[4][NKB];
#pragma unroll
        for (int mi = 0; mi < 4; ++mi)
#pragma unroll
            for (int kb = 0; kb < NKB; ++kb)
                ah[mi][kb] = zf[((size_t)(arb0 + mi) * NKB + kb) * 64 + l];

        unsigned b1[16], b2[16];
#pragma unroll
        for (int s = 0; s < 16; ++s) { b1[s] = 0u; b2[s] = 0u; }

        const char* gp[5];
#pragma unroll
        for (int ui = 0; ui < 5; ++ui) {
            const int u = w + ui * 4;
            const int uc = (u < AUNITS) ? u : 0;
            const int nj = uc / NKB, kb = uc - nj * NKB;
            gp[ui] = (const char*)&ef[((size_t)(sp * 32 + nj) * NKB + kb) * 64 + l];
        }

        auto stage = [&](size_t choff, int buf) {
            char* lb = (char*)&Bsm[0][0] + buf * (AUNITS * 1024);
#pragma unroll
            for (int ui = 0; ui < 5; ++ui) {
                const int u = w + ui * 4;
                if (u < AUNITS) g2l16(gp[ui] + choff, lb + u * 1024);
            }
        };

        auto ins = [&](unsigned key, int s) {
            unsigned b2n;
            asm("v_med3_u32 %0, %1, %2, %3"
                : "=v"(b2n) : "v"(key), "v"(b1[s]), "v"(b2[s]));
            b2[s] = b2n;
            b1[s] = umax(b1[s], key);
        };

        stage(0, 0);
        const f32x4 Zv = (f32x4){0.f, 0.f, 0.f, 0.f};
        int inv0 = 1023 - l15;
        for (int ch = 0; ch < NCH_A; ++ch) {
            const int buf = ch & 1;
            __syncthreads();
            if (ch + 1 < NCH_A) stage((size_t)(ch + 1) * 18432u, buf ^ 1);

            const unsigned invA = (unsigned)inv0;
            const unsigned invB = (unsigned)(inv0 - 16);

            f32x4 acc0[4], acc1[4];
            {
                const f16x8 bh = *(const f16x8*)&Bsm[buf][(0 * NKB + 0) * 512 + l * 8];
#pragma unroll
                for (int mi = 0; mi < 4; ++mi) acc0[mi] = MFMA16(ah[mi][0], bh, Zv);
            }
#pragma unroll
            for (int kb = 1; kb < NKB; ++kb) {
                const f16x8 bh = *(const f16x8*)&Bsm[buf][(0 * NKB + kb) * 512 + l * 8];
#pragma unroll
                for (int mi = 0; mi < 4; ++mi) acc0[mi] = MFMA16(ah[mi][kb], bh, acc0[mi]);
            }
            {
                const f16x8 bh = *(const f16x8*)&Bsm[buf][(1 * NKB + 0) * 512 + l * 8];
#pragma unroll
                for (int mi = 0; mi < 4; ++mi) acc1[mi] = MFMA16(ah[mi][0], bh, Zv);
            }
#pragma unroll
            for (int kb = 1; kb < NKB; ++kb) {
                const f16x8 bh = *(const f16x8*)&Bsm[buf][(1 * NKB + kb) * 512 + l * 8];
#pragma unroll
                for (int mi = 0; mi < 4; ++mi) acc1[mi] = MFMA16(ah[mi][kb], bh, acc1[mi]);
#pragma unroll
                for (int e = 2 * (kb - 1); e < 2 * (kb - 1) + 2; ++e) {
                    const int mi0 = e >> 2, r0 = e & 3;
                    ins((__float_as_uint(acc0[mi0][r0]) & 0xFFFFFC00u) | invA, e);
                }
            }
#pragma unroll
            for (int mi = 0; mi < 4; ++mi)
#pragma unroll
                for (int r = 0; r < 4; ++r)
                    ins((__float_as_uint(acc1[mi][r]) & 0xFFFFFC00u) | invB, mi * 4 + r);

            inv0 -= 32;
        }

#pragma unroll
        for (int s = 0; s < 16; ++s) {
            unsigned v1 = b1[s], v2 = b2[s];
#pragma unroll
            for (int m = 1; m <= 8; m <<= 1) {
                const unsigned o1 = __shfl_xor(v1, m);
                const unsigned o2 = __shfl_xor(v2, m);
                const unsigned n2 = umax(umin(v1, o1), umax(v2, o2));
                v1 = umax(v1, o1);
                v2 = n2;
            }
            if (l15 == 0) {
                const int mi = s >> 2, r = s & 3;
                const int row = row0 + w * 64 + mi * 16 + quad * 4 + r;
                kp1[(size_t)sp * NZ + row] = v1;
                kp2[(size_t)sp * NZ + row] = v2;
            }
        }
    } else {
        // ================= pairwise role (max-only) =================
        _Float16 (*Bsm)[PUNITS * 512] = (_Float16(*)[PUNITS * 512])Sh;
        int p = blockIdx.x - NBLK_ARG;
        int bi = 0;
        while (p >= NB - bi) { p -= NB - bi; ++bi; }
        const int bj = bi + p;
        const int row0 = bi * BM;
        const int c0 = bj * BM;

        float sR[8], sC[8];
#pragma unroll
        for (int mi = 0; mi < 2; ++mi)
#pragma unroll
            for (int r = 0; r < 4; ++r)
                sR[mi * 4 + r] = esq[row0 + w * 32 + mi * 16 + quad * 4 + r];
#pragma unroll
        for (int nj = 0; nj < 8; ++nj) sC[nj] = esq[c0 + nj * 16 + l15];

        const int arb = bi * 8 + w * 2;
        const int cfb = bj * 8;

        f16x8 ah[2][NKB_P];
#pragma unroll
        for (int kb = 0; kb < NKB_P; ++kb) {
            ah[0][kb] = ef[((size_t)arb * NKB + kb) * 64 + l];
            ah[1][kb] = ef[((size_t)(arb + 1) * NKB + kb) * 64 + l];
        }

        float rmx[8], cmx[8];
#pragma unroll
        for (int s = 0; s < 8; ++s) { rmx[s] = 0.f; cmx[s] = 0.f; }

        auto stage = [&](int ch, int buf) {
            for (int u = w; u < PUNITS; u += 4) {
                const int nj = u >> 3, kb = u & 7;
                g2l16(&ef[((size_t)(cfb + ch * 2 + nj) * NKB + kb) * 64 + l],
                      &Bsm[buf][u * 512]);
            }
        };

        stage(0, 0);
        for (int ch = 0; ch < 4; ++ch) {            // 4 chunks x 32 cols = 128
            const int buf = ch & 1;
            __syncthreads();
            if (ch + 1 < 4) stage(ch + 1, buf ^ 1);

            f32x4 acc[2][2];
#pragma unroll
            for (int mi = 0; mi < 2; ++mi)
#pragma unroll
                for (int nj = 0; nj < 2; ++nj) acc[mi][nj] = (f32x4){0.f, 0.f, 0.f, 0.f};

#pragma unroll
            for (int kb = 0; kb < NKB_P; ++kb) {
                const f16x8 bh0 = *(const f16x8*)&Bsm[buf][(0 * 8 + kb) * 512 + l * 8];
                const f16x8 bh1 = *(const f16x8*)&Bsm[buf][(1 * 8 + kb) * 512 + l * 8];
#pragma unroll
                for (int mi = 0; mi < 2; ++mi) {
                    acc[mi][0] = MFMA16(ah[mi][kb], bh0, acc[mi][0]);
                    acc[mi][1] = MFMA16(ah[mi][kb], bh1, acc[mi][1]);
                }
            }

#pragma unroll
            for (int nj = 0; nj < 2; ++nj) {
                const int cidx = ch * 2 + nj;
#pragma unroll
                for (int mi = 0; mi < 2; ++mi)
#pragma unroll
                    for (int r = 0; r < 4; ++r) {
                        const int s = mi * 4 + r;
                        const float t1 = __fadd_rn(sR[s], sC[cidx]);
                        const float d2 = fmaf(-0x1p-25f, acc[mi][nj][r], t1);
                        const float d2c = fmaxf(d2, 0.f);
                        rmx[s] = fmaxf(rmx[s], d2c);
                        cmx[cidx] = fmaxf(cmx[cidx], d2c);
                    }
            }
        }

        // rows: butterfly across the 16 lanes of the quad group, then atomics
#pragma unroll
        for (int s = 0; s < 8; ++s) {
#pragma unroll
            for (int m = 1; m <= 8; m <<= 1)
                rmx[s] = fmaxf(rmx[s], __shfl_xor(rmx[s], m));
        }
        if (l15 == 0) {
#pragma unroll
            for (int s = 0; s < 8; ++s) {
                const int mi = s >> 2, r = s & 3;
                const int row = row0 + w * 32 + mi * 16 + quad * 4 + r;
                atomicMax(&rmxg[row], __float_as_uint(rmx[s]));
            }
        }

        // cols: butterfly across quads, LDS across waves (reuse Bsm), then atomics
#pragma unroll
        for (int nj = 0; nj < 8; ++nj) {
#pragma unroll
            for (int m = 16; m <= 32; m <<= 1)
                cmx[nj] = fmaxf(cmx[nj], __shfl_xor(cmx[nj], m));
        }
        __syncthreads();   // all chunk reads done; Bsm reusable
        float* Mx = (float*)&Bsm[0][0];          // [4][128]
        if (quad == 0) {
#pragma unroll
            for (int nj = 0; nj < 8; ++nj)
                Mx[w * 128 + nj * 16 + l15] = cmx[nj];
        }
        __syncthreads();
        if (t < BM) {
            float mx = Mx[t];
#pragma unroll
            for (int ww = 1; ww < 4; ++ww)
                mx = fmaxf(mx, Mx[ww * 128 + t]);
            atomicMax(&rmxg[c0 + t], __float_as_uint(mx));
        }
    }
}

// merge split keys (transposed [sp][row] layout -> coalesced reads);
// provisional idx; per-split top-1 candidates for near-tie rows; full-split
// fallback only when a split's SECOND-best is also in range.
__global__ __launch_bounds__(256) void k_merge(const unsigned* __restrict__ kp1,
                                               const unsigned* __restrict__ kp2,
                                               int* __restrict__ idxbuf,
                                               float* __restrict__ outidx,
                                               int* __restrict__ cnt,
                                               int* __restrict__ lists,
                                               unsigned long long* __restrict__ cand) {
    const int n = blockIdx.x * 256 + threadIdx.x;
    unsigned k1v[NSPLIT_A], k2v[NSPLIT_A];
#pragma unroll
    for (int s = 0; s < NSPLIT_A; ++s) {
        k1v[s] = kp1[(size_t)s * NZ + n];
        k2v[s] = kp2[(size_t)s * NZ + n];
    }
    unsigned K1 = k1v[0]; int sb = 0;
#pragma unroll
    for (int s = 1; s < NSPLIT_A; ++s)
        if (k1v[s] > K1) { K1 = k1v[s]; sb = s; }
    unsigned K2 = 0u;
#pragma unroll
    for (int s = 0; s < NSPLIT_A; ++s) {
        const unsigned a = (s == sb) ? k2v[s] : k1v[s];
        K2 = umax(K2, a);
    }
    const int ii1 = sb * SPLIT_NA + 1023 - (int)(K1 & 1023u);
    idxbuf[n] = ii1;
    outidx[n] = (float)ii1;
    const float val1 = __uint_as_float(K1 & 0xFFFFFC00u);
    const float val2 = __uint_as_float(K2 & 0xFFFFFC00u);
    if (val1 - val2 < GAPTH_EFF) {
        const float vlim = val1 - GAPTH_EFF;    // qualify: val >= vlim
        int ncand = 0;
#pragma unroll
        for (int s = 0; s < NSPLIT_A; ++s) {
            if (__uint_as_float(k1v[s] & 0xFFFFFC00u) >= vlim) ++ncand;
            if (__uint_as_float(k2v[s] & 0xFFFFFC00u) >= vlim) {
                const int p = atomicAdd(&cnt[s], 1);
                lists[s * NZ + p] = n;
            }
        }
        const int base = atomicAdd(&cnt[16], ncand);
        int o = 0;
#pragma unroll
        for (int s = 0; s < NSPLIT_A; ++s)
            if (__uint_as_float(k1v[s] & 0xFFFFFC00u) >= vlim) {
                const int col = s * SPLIT_NA + 1023 - (int)(k1v[s] & 1023u);
                cand[base + o] = ((unsigned long long)(unsigned)n << 32) |
                                 (unsigned)col;
                ++o;
            }
    }
}

// ---- fused fp32 repair: blocks [0,1024) = fix_split role (np-bit-exact,
// exact (s,chunk,rb) mapping of the former 2D grid: x=bx&63, y=bx>>6);
// blocks [1024,1152) = fix_cand role (bit-identical fmaf chain).
__global__ __launch_bounds__(256) void k_fix(const float* __restrict__ z,
                                             const float* __restrict__ emb,
                                             const float* __restrict__ zsq,
                                             const float* __restrict__ esq,
                                             const int* __restrict__ cnt,
                                             const int* __restrict__ lists,
                                             const unsigned long long* __restrict__ cand,
                                             unsigned long long* __restrict__ pack) {
    __shared__ float As[BK * LDA];
    __shared__ float Bs[BK * LDA];
    __shared__ float Sq[BM];
    __shared__ int frow[BM];

    const int t = threadIdx.x;
    if (blockIdx.x >= 1024) {
        // ================= fix_cand role =================
        const int nc = cnt[16];
        for (int i = (blockIdx.x - 1024) * 256 + t; i < nc; i += 128 * 256) {
            const unsigned long long pr = cand[i];
            const int row = (int)(pr >> 32);
            const int col = (int)(pr & 0xffffffffu);
            const float4* zp = (const float4*)(z + (size_t)row * D);
            const float4* ep = (const float4*)(emb + (size_t)col * D);
            float acc = 0.f;
#pragma unroll
            for (int k4 = 0; k4 < D / 4; ++k4) {
                const float4 a = zp[k4];
                const float4 b = ep[k4];
                acc = fmaf(a.x, b.x, acc);
                acc = fmaf(a.y, b.y, acc);
                acc = fmaf(a.z, b.z, acc);
                acc = fmaf(a.w, b.w, acc);
            }
            const float sc = fmaf(-2.f, acc, __fadd_rn(zsq[row], esq[col]));
            const unsigned long long pk =
                ((unsigned long long)__float_as_uint(sc) << 32) | (unsigned)col;
            atomicMin(&pack[row], pk);
        }
        return;
    }

    // ================= fix_split role =================
    const int bx = blockIdx.x;
    const int xl = bx & 63;
    const int s = xl >> 2;
    const int chunk = xl & 3;
    const int ns = cnt[s];
    const int c0 = s * SPLIT_NA + chunk * BM;
    const int tr = t >> 4;
    const int tc = t & 15;
    const int sr = t >> 3;
    const int skq = t & 7;
    const int wrot = 8 * (skq & 3);

    for (int rb = bx >> 6; rb * BM < ns; rb += 16) {
        __syncthreads();
        if (t < BM) {
            const int fi = rb * BM + t;
            frow[t] = (fi < ns) ? lists[s * NZ + fi] : lists[s * NZ];
            Sq[t] = esq[c0 + t];
        }
        __syncthreads();

        float zqr[8];
#pragma unroll
        for (int i = 0; i < 8; ++i) zqr[i] = zsq[frow[tr * 8 + i]];

        float best[8];
        int bidx[8];
#pragma unroll
        for (int i = 0; i < 8; ++i) { best[i] = 3.4e38f; bidx[i] = 0; }

        float acc[8][8];
#pragma unroll
        for (int i = 0; i < 8; ++i)
#pragma unroll
            for (int j = 0; j < 8; ++j) acc[i][j] = 0.f;

        float4 pav[4], pbv[4];
#pragma unroll
        for (int q = 0; q < 4; ++q) {
            const int r = sr + 32 * q;
            pav[q] = *(const float4*)&z[(size_t)frow[r] * D + 0 + 4 * skq];
            pbv[q] = *(const float4*)&emb[(size_t)(c0 + r) * D + 0 + 4 * skq];
        }

        for (int kb = 0; kb < D; kb += BK) {
            __syncthreads();
#pragma unroll
            for (int q = 0; q < 4; ++q) {
                const int r = sr + 32 * q;
                const int rr = (r + wrot) & 127;
                As[(4 * skq + 0) * LDA + rr] = pav[q].x;
                As[(4 * skq + 1) * LDA + rr] = pav[q].y;
                As[(4 * skq + 2) * LDA + rr] = pav[q].z;
                As[(4 * skq + 3) * LDA + rr] = pav[q].w;
                Bs[(4 * skq + 0) * LDA + rr] = pbv[q].x;
                Bs[(4 * skq + 1) * LDA + rr] = pbv[q].y;
                Bs[(4 * skq + 2) * LDA + rr] = pbv[q].z;
                Bs[(4 * skq + 3) * LDA + rr] = pbv[q].w;
            }
            __syncthreads();
            if (kb + BK < D) {
#pragma unroll
                for (int q = 0; q < 4; ++q) {
                    const int r = sr + 32 * q;
                    pav[q] = *(const float4*)&z[(size_t)frow[r] * D + kb + BK + 4 * skq];
                    pbv[q] = *(const float4*)&emb[(size_t)(c0 + r) * D + kb + BK + 4 * skq];
                }
            }
#pragma unroll
            for (int k = 0; k < BK; ++k) {
                const float4 a0 = *(const float4*)&As[k * LDA + SWZR(k, tr * 8)];
                const float4 a1 = *(const float4*)&As[k * LDA + SWZR(k, tr * 8 + 4)];
                const float4 b0 = *(const float4*)&Bs[k * LDA + SWZR(k, tc * 4)];
                const float4 b1 = *(const float4*)&Bs[k * LDA + SWZR(k, 64 + tc * 4)];
                const float a[8] = {a0.x, a0.y, a0.z, a0.w, a1.x, a1.y, a1.z, a1.w};
                const float b[8] = {b0.x, b0.y, b0.z, b0.w, b1.x, b1.y, b1.z, b1.w};
#pragma unroll
                for (int i = 0; i < 8; ++i)
#pragma unroll
                    for (int j = 0; j < 8; ++j)
                        acc[i][j] = fmaf(a[i], b[j], acc[i][j]);
            }
        }
#pragma unroll
        for (int jj = 0; jj < 8; ++jj) {
            const int cloc = (jj < 4) ? (tc * 4 + jj) : (64 + tc * 4 + (jj - 4));
            const float sq = Sq[cloc];
            const int gcol = c0 + cloc;
#pragma unroll
            for (int i = 0; i < 8; ++i) {
                const float t1 = __fadd_rn(zqr[i], sq);
                const float sc = fmaf(-2.f, acc[i][jj], t1);
                if (sc < best[i]) { best[i] = sc; bidx[i] = gcol; }
            }
        }
        __syncthreads();

        float* Rs = As;
        int* Ri = (int*)Bs;
#pragma unroll
        for (int i = 0; i < 8; ++i) {
            Rs[(tr * 8 + i) * LDM + tc] = best[i];
            Ri[(tr * 8 + i) * LDM + tc] = bidx[i];
        }
        __syncthreads();
        if (t < BM) {
            float bs = Rs[t * LDM];
            int bi = Ri[t * LDM];
#pragma unroll
            for (int c = 1; c < 16; ++c) {
                const float sc = Rs[t * LDM + c];
                const int ii = Ri[t * LDM + c];
                if (sc < bs || (sc == bs && ii < bi)) { bs = sc; bi = ii; }
            }
            const int fi = rb * BM + t;
            if (fi < ns) {
                const unsigned long long pk =
                    ((unsigned long long)__float_as_uint(bs) << 32) | (unsigned)bi;
                atomicMin(&pack[frow[t]], pk);
            }
        }
    }
}

// gather z_q into out (fused fixdecode: pack overrides provisional idx);
// per-block partial of sum((z_q-z)^2) -> gpart (NO atomics)
__global__ __launch_bounds__(256) void k_gather(const float* __restrict__ z,
                                                const float* __restrict__ emb,
                                                const int* __restrict__ idxbuf,
                                                const unsigned long long* __restrict__ pack,
                                                float* __restrict__ out,
                                                float* __restrict__ outidx,
                                                double* __restrict__ gpart) {
    __shared__ double part[4];
    const int row = blockIdx.x * 4 + (threadIdx.x >> 6);
    const int lane = threadIdx.x & 63;
    const unsigned long long p = pack[row];
    const int idx = (p != ~0ull) ? (int)(p & 0xffffffffu) : idxbuf[row];
    if (lane == 0) outidx[row] = (float)idx;
    const float4 e4 = *(const float4*)&emb[(size_t)idx * D + lane * 4];
    const float4 z4 = *(const float4*)&z[(size_t)row * D + lane * 4];
    *(float4*)&out[(size_t)row * D + lane * 4] = e4;
    const float dx = e4.x - z4.x, dy = e4.y - z4.y;
    const float dzv = e4.z - z4.z, dw = e4.w - z4.w;
    float s = dx * dx + dy * dy + dzv * dzv + dw * dw;
    s = waveReduceSumF(s);
    if (lane == 0) part[threadIdx.x >> 6] = (double)s;
    __syncthreads();
    if (threadIdx.x == 0)
        gpart[blockIdx.x] = part[0] + part[1] + part[2] + part[3];
}

// final reduce (1024 threads): gather-partials + max-range sum (min==0
// provably) + esq sum
__global__ __launch_bounds__(1024) void k_final(const double* __restrict__ gpart,
                                                const float* __restrict__ esq,
                                                const unsigned* __restrict__ rmxg,
                                                float* __restrict__ out) {
    __shared__ double part[16];
    __shared__ double partm[16];
    __shared__ double parte[16];
    const int t = threadIdx.x;
    double s = 0.0;
#pragma unroll
    for (int i = 0; i < NGB / 1024; ++i) s += gpart[i * 1024 + t];
    s = waveReduceSumD(s);
    double m = 0.0, e2 = 0.0;
#pragma unroll
    for (int i = 0; i < NE / 1024; ++i) {
        const int n = i * 1024 + t;
        m += (double)sqrtf(__uint_as_float(rmxg[n]));
        e2 += (double)esq[n];
    }
    m = waveReduceSumD(m);
    e2 = waveReduceSumD(e2);
    if ((t & 63) == 0) { part[t >> 6] = s; partm[t >> 6] = m; parte[t >> 6] = e2; }
    __syncthreads();
    if (t == 0) {
        double diff2 = 0.0, msum = 0.0, esum = 0.0;
#pragma unroll
        for (int i = 0; i < 16; ++i) {
            diff2 += part[i]; msum += partm[i]; esum += parte[i];
        }
        const double loss = 1.25 * (diff2 / (double)((size_t)NZ * D));
        const double qq = 0.1 * (msum / (double)NE) + 0.1 * esum;
        out[(size_t)NZ * D + NZ] = (float)loss;
        out[(size_t)NZ * D + NZ + 1] = (float)qq;
    }
}

extern "C" void kernel_launch(void* const* d_in, const int* in_sizes, int n_in,
                              void* d_out, int out_size, void* d_ws, size_t ws_size,
                              hipStream_t stream) {
    const float* z = (const float*)d_in[0];
    const float* emb = (const float*)d_in[1];
    float* out = (float*)d_out;
    char* ws = (char*)d_ws;

    int* cnt = (int*)(ws + WS_CNT);
    float* zsq = (float*)(ws + WS_ZSQ);
    float* esq = (float*)(ws + WS_ESQ);
    int* idxb = (int*)(ws + WS_IDX);
    unsigned* kp1 = (unsigned*)(ws + WS_KP1);
    unsigned* kp2 = (unsigned*)(ws + WS_KP2);
    unsigned* rmx = (unsigned*)(ws + WS_RMX);
    unsigned long long* pack = (unsigned long long*)(ws + WS_PACK);
    double* gpart = (double*)(ws + WS_GPART);
    int* lists = (int*)(ws + WS_LISTS);
    f16x8* zhf = (f16x8*)(ws + WS_ZHF);
    f16x8* ehf = (f16x8*)(ws + WS_EHF);
    unsigned long long* cand = (unsigned long long*)(ws + WS_CAND);
    float* outidx = out + (size_t)NZ * D;

    hipLaunchKernelGGL(k_cvt, dim3(NBLK_CVT), dim3(256), 0, stream,
                       z, emb, zhf, ehf, zsq, esq, cnt, rmx, pack);
    hipLaunchKernelGGL(k_big, dim3(NBLK_BIG), dim3(256), 0, stream,
                       zhf, ehf, esq, kp1, kp2, rmx);
    hipLaunchKernelGGL(k_merge, dim3(NZ / 256), dim3(256), 0, stream,
                       kp1, kp2, idxb, outidx, cnt, lists, cand);
    hipLaunchKernelGGL(k_fix, dim3(NBLK_FIX), dim3(256), 0, stream,
                       z, emb, zsq, esq, cnt, lists, cand, pack);
    hipLaunchKernelGGL(k_gather, dim3(NGB), dim3(256), 0, stream,
                       z, emb, idxb, pack, out, outidx, gpart);
    hipLaunchKernelGGL(k_final, dim3(1), dim3(1024), 0, stream,
                       gpart, esq, rmx, out);
}